// Round 9
// baseline (155.719 us; speedup 1.0000x reference)
//
#include <hip/hip_runtime.h>

#define BB 2
#define NN 6272
#define CC 256
#define CI 128
#define SEG 7
#define KVSEG (NN / SEG)          // 896 kv per segment, 28 tiles of 32
#define NIT (KVSEG / 32)
#define LOG2E 1.44269504088896f
#define THR 12.0f                 // defer-max threshold (log2 domain), P <= 4096 fits f16

typedef _Float16 f16;
typedef __attribute__((ext_vector_type(2))) __fp16 fp16v2;   // cvt_pkrtz native type
typedef __attribute__((ext_vector_type(8))) _Float16 f16x8;
typedef __attribute__((ext_vector_type(4))) float f32x4;

// ---------------- kernel 0: weight prep (once, ~3us) ----------------
__global__ __launch_bounds__(256) void prep_kernel(
    const float* __restrict__ Wg, const float* __restrict__ Wt, const float* __restrict__ Wp,
    const float* __restrict__ Wo, const float* __restrict__ bg, const float* __restrict__ bt,
    const float* __restrict__ bp, const float* __restrict__ bo,
    const float* __restrict__ gamma, const float* __restrict__ beta,
    const float* __restrict__ mmean, const float* __restrict__ mvar,
    f16* __restrict__ WallT, f16* __restrict__ WoT,
    float* __restrict__ ball, float* __restrict__ bnsc, float* __restrict__ bnsh)
{
    const int idx = blockIdx.x * 256 + threadIdx.x;
    if (idx < 384*256) {
        const int j = idx >> 8, k = idx & 255;
        float v;
        if (j < 128)      v = Wg[k*CI + j];
        else if (j < 256) v = Wt[k*CI + (j-128)] * LOG2E;
        else              v = Wp[k*CI + (j-256)];
        WallT[j*256 + k] = (f16)v;
    } else if (idx < 384*256 + 256*128) {
        const int i2 = idx - 384*256;
        const int ci = i2 >> 7, k = i2 & 127;
        WoT[ci*CI + k] = (f16)Wo[k*CC + ci];
    } else {
        const int i3 = idx - (384*256 + 256*128);
        if (i3 < 384) {
            float v;
            if (i3 < 128)      v = bg[i3];
            else if (i3 < 256) v = bt[i3-128] * LOG2E;
            else               v = bp[i3-256];
            ball[i3] = v;
        } else if (i3 < 640) {
            const int c = i3 - 384;
            bnsc[c] = gamma[c] * rsqrtf(mvar[c] + 1e-3f);
        } else if (i3 < 896) {
            const int c = i3 - 640;
            float sc = gamma[c] * rsqrtf(mvar[c] + 1e-3f);
            bnsh[c] = beta[c] + sc * (bo[c] - mmean[c]);
        }
    }
}

// ---------------- kernel 1: fused projection GEMM (MFMA) ----------------
// gT tiled: [b][n/32][ci][32]  (32-kv tiles, contiguous 8KB per tile)
__global__ __launch_bounds__(256) void proj_gemm(
    const float* __restrict__ x, const f16* __restrict__ WallT, const float* __restrict__ ball,
    f16* __restrict__ th, f16* __restrict__ ph, f16* __restrict__ gT)
{
    __shared__ __align__(16) f16 xls[16*264];
    __shared__ __align__(16) f16 gls[128*24];

    const int tid = threadIdx.x;
    const int wid = tid >> 6, lane = tid & 63;
    const int l15 = lane & 15, lg = lane >> 4;
    const int p0 = blockIdx.x * 16;
    const int nq = wid;

    {   // stage x tile 16x256 -> f16 LDS
        const int row = tid >> 4, seg = (tid & 15) * 16;
        const float* xsrc = x + (size_t)(p0 + row) * CC + seg;
        f16 buf[16];
        #pragma unroll
        for (int i = 0; i < 4; ++i) {
            float4 v = *reinterpret_cast<const float4*>(xsrc + 4*i);
            buf[4*i+0]=(f16)v.x; buf[4*i+1]=(f16)v.y; buf[4*i+2]=(f16)v.z; buf[4*i+3]=(f16)v.w;
        }
        *reinterpret_cast<f16x8*>(&xls[row*264 + seg])     = *reinterpret_cast<f16x8*>(&buf[0]);
        *reinterpret_cast<f16x8*>(&xls[row*264 + seg + 8]) = *reinterpret_cast<f16x8*>(&buf[8]);
    }
    __syncthreads();

    f32x4 acc[6];
    #pragma unroll
    for (int t = 0; t < 6; ++t) acc[t] = (f32x4){0.f,0.f,0.f,0.f};

    const f16* wbase = WallT + (size_t)(nq*96 + l15)*256 + lg*8;
    for (int kk = 0; kk < 8; ++kk) {
        f16x8 a = *reinterpret_cast<const f16x8*>(&xls[l15*264 + kk*32 + lg*8]);
        #pragma unroll
        for (int t = 0; t < 6; ++t) {
            f16x8 bfr = *reinterpret_cast<const f16x8*>(wbase + (size_t)t*16*256 + kk*32);
            acc[t] = __builtin_amdgcn_mfma_f32_16x16x32_f16(a, bfr, acc[t], 0, 0, 0);
        }
    }

    const int bidx = (p0 >= NN) ? 1 : 0;
    const int n0 = p0 - bidx * NN;
    const int prow = lg * 4;

    #pragma unroll
    for (int t = 0; t < 6; ++t) {
        const int j0 = nq*96 + t*16;          // + l15 per lane
        const float bv = ball[j0 + l15];
        if (j0 < 128) {          // g -> LDS transpose
            #pragma unroll
            for (int r = 0; r < 4; ++r)
                gls[(j0 + l15)*24 + prow + r] = (f16)(acc[t][r] + bv);
        } else if (j0 < 256) {   // theta (pre-scaled)
            f16* dst = th + (size_t)(p0 + prow)*CI + (j0 - 128) + l15;
            #pragma unroll
            for (int r = 0; r < 4; ++r)
                dst[(size_t)r*CI] = (f16)(acc[t][r] + bv);
        } else {                 // phi
            f16* dst = ph + (size_t)(p0 + prow)*CI + (j0 - 256) + l15;
            #pragma unroll
            for (int r = 0; r < 4; ++r)
                dst[(size_t)r*CI] = (f16)(acc[t][r] + bv);
        }
    }
    __syncthreads();
    {   // tiled gT store: [b][n/32][ci][32]
        const int ci = tid >> 1, part = tid & 1;
        f16x8 v = *reinterpret_cast<const f16x8*>(&gls[ci*24 + part*8]);
        f16* gdst = gT + ((size_t)bidx*(NN/32) + (n0 >> 5))*(CI*32)
                       + ci*32 + (n0 & 16) + part*8;
        *reinterpret_cast<f16x8*>(gdst) = v;
    }
}

// ---------------- kernel 2: split-KV flash attention, 1-tile software pipeline -------
// grid (NN/128, SEG, BB); 4 waves/block; wave owns 32 q rows. KV tile = 32.
// S(t) held in registers across iterations. Loop body:
//   issue loads(t+2) -> QK(t+1) MFMAs (results needed next iter: infinite slack)
//   -> softmax(t) (VALU, overlaps QK retire) -> pa(t) -> PV(t)
//   -> [barrier; stage tile t+2 -> buf[t&1]; barrier]   (skipped for last 2 iters)
// buf[t&1] = tile t (g for PV), buf[(t+1)&1] = tile t+1 (phi for QK).
__global__ __launch_bounds__(256, 3) void attn_kernel(
    const f16* __restrict__ th, const f16* __restrict__ ph,
    const f16* __restrict__ gT, float* __restrict__ pacc, float* __restrict__ pml)
{
    __shared__ __align__(16) f16 ph_lds[2][32 * 128];  // dbuf [kv][c], swizzled
    __shared__ __align__(16) f16 g_lds[2][128 * 32];   // dbuf [ci][kv], swizzled
    __shared__ __align__(16) f16 pT_lds[4][2][16][40]; // per-wave [qt][q][kv+pad]

    const int b   = blockIdx.z;
    const int seg = blockIdx.y;
    const int tid = threadIdx.x;
    const int wid = tid >> 6;
    const int lane = tid & 63;
    const int l15 = lane & 15;
    const int lg  = lane >> 4;
    const int qw  = blockIdx.x * 128 + wid * 32;

    const f16* thb = th + (size_t)b * NN * CI;
    const f16* phb = ph + (size_t)b * NN * CI;
    const f16* gTb = gT + (size_t)b * (NN/32) * (CI*32);

    // persistent theta B-frags: 2 q-tiles x 4 k-frags
    f16x8 bf[2][4];
    #pragma unroll
    for (int qt = 0; qt < 2; ++qt) {
        const f16* trow = thb + (size_t)(qw + qt*16 + l15) * CI + lg * 8;
        #pragma unroll
        for (int kk = 0; kk < 4; ++kk)
            bf[qt][kk] = *reinterpret_cast<const f16x8*>(trow + kk * 32);
    }

    f32x4 acc[2][8];              // Y^T: per q-tile, 8 ci-tiles, col=q
    f32x4 accl[2];                // row-sums (ones trick)
    float m[2] = {-INFINITY, -INFINITY};
    #pragma unroll
    for (int qt = 0; qt < 2; ++qt) {
        #pragma unroll
        for (int ct = 0; ct < 8; ++ct) acc[qt][ct] = (f32x4){0.f,0.f,0.f,0.f};
        accl[qt] = (f32x4){0.f,0.f,0.f,0.f};
    }

    const f16x8 onesA = {(f16)1,(f16)1,(f16)1,(f16)1,(f16)1,(f16)1,(f16)1,(f16)1};

    // phi staging: 32 rows x 128 c, XOR-swizzled
    const int prow = tid >> 3, pcol = (tid & 7) * 16;
    const int pswz = (prow & 7) << 3;
    const int pc0 = pcol ^ pswz, pc1 = (pcol + 8) ^ pswz;
    // g staging: 128 rows x 32 kv, XOR-swizzled; source tile contiguous 8KB
    const int grow = tid >> 1, gcs = (tid & 1) * 16;
    const int gswz = ((grow >> 1) & 3) << 3;
    const int gc0 = gcs ^ gswz, gc1 = (gcs + 8) ^ gswz;

    const int kv_base = seg * KVSEG;
    const int t0 = kv_base >> 5;            // first g tile index
    const int xsw = (l15 & 7) << 3;

    // ---- prologue: stage tile 0 ----
    {
        const f16* ps = phb + (size_t)(kv_base + prow) * CI + pcol;
        f16x8 a = *reinterpret_cast<const f16x8*>(ps);
        f16x8 c = *reinterpret_cast<const f16x8*>(ps + 8);
        const f16* gs = gTb + (size_t)t0 * (CI*32) + tid * 16;
        f16x8 g0 = *reinterpret_cast<const f16x8*>(gs);
        f16x8 g1 = *reinterpret_cast<const f16x8*>(gs + 8);
        *reinterpret_cast<f16x8*>(&ph_lds[0][prow*128 + pc0]) = a;
        *reinterpret_cast<f16x8*>(&ph_lds[0][prow*128 + pc1]) = c;
        *reinterpret_cast<f16x8*>(&g_lds[0][grow*32 + gc0])   = g0;
        *reinterpret_cast<f16x8*>(&g_lds[0][grow*32 + gc1])   = g1;
    }
    __syncthreads();

    // ---- prologue: issue tile-1 loads, QK(0), stage tile 1 ----
    f32x4 s00, s01, s10, s11;
    {
        const f16* ps = phb + (size_t)(kv_base + 32 + prow) * CI + pcol;
        f16x8 pv0 = *reinterpret_cast<const f16x8*>(ps);
        f16x8 pv1 = *reinterpret_cast<const f16x8*>(ps + 8);
        const f16* gs = gTb + (size_t)(t0 + 1) * (CI*32) + tid * 16;
        f16x8 gv0 = *reinterpret_cast<const f16x8*>(gs);
        f16x8 gv1 = *reinterpret_cast<const f16x8*>(gs + 8);

        s00 = (f32x4){0.f,0.f,0.f,0.f}; s01 = (f32x4){0.f,0.f,0.f,0.f};
        s10 = (f32x4){0.f,0.f,0.f,0.f}; s11 = (f32x4){0.f,0.f,0.f,0.f};
        #pragma unroll
        for (int kk = 0; kk < 4; ++kk) {
            const int coff = (kk*32 + lg*8) ^ xsw;
            f16x8 a0 = *reinterpret_cast<const f16x8*>(&ph_lds[0][l15*128 + coff]);
            f16x8 a1 = *reinterpret_cast<const f16x8*>(&ph_lds[0][(16 + l15)*128 + coff]);
            s00 = __builtin_amdgcn_mfma_f32_16x16x32_f16(a0, bf[0][kk], s00, 0, 0, 0);
            s01 = __builtin_amdgcn_mfma_f32_16x16x32_f16(a1, bf[0][kk], s01, 0, 0, 0);
            s10 = __builtin_amdgcn_mfma_f32_16x16x32_f16(a0, bf[1][kk], s10, 0, 0, 0);
            s11 = __builtin_amdgcn_mfma_f32_16x16x32_f16(a1, bf[1][kk], s11, 0, 0, 0);
        }
        *reinterpret_cast<f16x8*>(&ph_lds[1][prow*128 + pc0]) = pv0;
        *reinterpret_cast<f16x8*>(&ph_lds[1][prow*128 + pc1]) = pv1;
        *reinterpret_cast<f16x8*>(&g_lds[1][grow*32 + gc0])   = gv0;
        *reinterpret_cast<f16x8*>(&g_lds[1][grow*32 + gc1])   = gv1;
    }
    __syncthreads();

    #pragma unroll 1
    for (int it = 0; it < NIT; ++it) {
        const int cur = it & 1, nxt = cur ^ 1;
        const bool have2 = (it + 2 < NIT);
        const int it2 = have2 ? (it + 2) : (NIT - 1);

        // ---- issue tile t+2 loads (land during this iteration's compute) ----
        const f16* ps = phb + (size_t)(kv_base + it2*32 + prow) * CI + pcol;
        f16x8 pv0 = *reinterpret_cast<const f16x8*>(ps);
        f16x8 pv1 = *reinterpret_cast<const f16x8*>(ps + 8);
        const f16* gs = gTb + (size_t)(t0 + it2) * (CI*32) + tid * 16;
        f16x8 gv0 = *reinterpret_cast<const f16x8*>(gs);
        f16x8 gv1 = *reinterpret_cast<const f16x8*>(gs + 8);

        // ---- QK(t+1) from buf[nxt] (results needed next iter -> full slack) ----
        f32x4 n00 = (f32x4){0.f,0.f,0.f,0.f}, n01 = (f32x4){0.f,0.f,0.f,0.f};
        f32x4 n10 = (f32x4){0.f,0.f,0.f,0.f}, n11 = (f32x4){0.f,0.f,0.f,0.f};
        if (it + 1 < NIT) {
            const f16* cb = &ph_lds[nxt][0];
            #pragma unroll
            for (int kk = 0; kk < 4; ++kk) {
                const int coff = (kk*32 + lg*8) ^ xsw;
                f16x8 a0 = *reinterpret_cast<const f16x8*>(&cb[l15*128 + coff]);
                f16x8 a1 = *reinterpret_cast<const f16x8*>(&cb[(16 + l15)*128 + coff]);
                n00 = __builtin_amdgcn_mfma_f32_16x16x32_f16(a0, bf[0][kk], n00, 0, 0, 0);
                n01 = __builtin_amdgcn_mfma_f32_16x16x32_f16(a1, bf[0][kk], n01, 0, 0, 0);
                n10 = __builtin_amdgcn_mfma_f32_16x16x32_f16(a0, bf[1][kk], n10, 0, 0, 0);
                n11 = __builtin_amdgcn_mfma_f32_16x16x32_f16(a1, bf[1][kk], n11, 0, 0, 0);
            }
        }

        // ---- softmax(t) on held s-regs (VALU; overlaps QK retire) ----
        float tm0 = fmaxf(fmaxf(fmaxf(s00[0], s00[1]), fmaxf(s00[2], s00[3])),
                          fmaxf(fmaxf(s01[0], s01[1]), fmaxf(s01[2], s01[3])));
        float tm1 = fmaxf(fmaxf(fmaxf(s10[0], s10[1]), fmaxf(s10[2], s10[3])),
                          fmaxf(fmaxf(s11[0], s11[1]), fmaxf(s11[2], s11[3])));
        tm0 = fmaxf(tm0, __shfl_xor(tm0, 16));
        tm0 = fmaxf(tm0, __shfl_xor(tm0, 32));
        tm1 = fmaxf(tm1, __shfl_xor(tm1, 16));
        tm1 = fmaxf(tm1, __shfl_xor(tm1, 32));
        if (__any((tm0 > m[0] + THR) || (tm1 > m[1] + THR))) {
            float nm0 = fmaxf(m[0], tm0), nm1 = fmaxf(m[1], tm1);
            float sc0 = __builtin_amdgcn_exp2f(m[0] - nm0);
            float sc1 = __builtin_amdgcn_exp2f(m[1] - nm1);
            m[0] = nm0; m[1] = nm1;
            #pragma unroll
            for (int ct = 0; ct < 8; ++ct) {
                acc[0][ct][0] *= sc0; acc[0][ct][1] *= sc0; acc[0][ct][2] *= sc0; acc[0][ct][3] *= sc0;
                acc[1][ct][0] *= sc1; acc[1][ct][1] *= sc1; acc[1][ct][2] *= sc1; acc[1][ct][3] *= sc1;
            }
            accl[0][0] *= sc0; accl[0][1] *= sc0; accl[0][2] *= sc0; accl[0][3] *= sc0;
            accl[1][0] *= sc1; accl[1][1] *= sc1; accl[1][2] *= sc1; accl[1][3] *= sc1;
        }

        // ---- P(t) = exp2(s - m), pack f16, exchange via per-wave LDS ----
        {
            union { fp16v2 h[2]; float2 f; } u0, u1;
            u0.h[0] = __builtin_amdgcn_cvt_pkrtz(__builtin_amdgcn_exp2f(s00[0] - m[0]),
                                                 __builtin_amdgcn_exp2f(s00[1] - m[0]));
            u0.h[1] = __builtin_amdgcn_cvt_pkrtz(__builtin_amdgcn_exp2f(s00[2] - m[0]),
                                                 __builtin_amdgcn_exp2f(s00[3] - m[0]));
            u1.h[0] = __builtin_amdgcn_cvt_pkrtz(__builtin_amdgcn_exp2f(s01[0] - m[0]),
                                                 __builtin_amdgcn_exp2f(s01[1] - m[0]));
            u1.h[1] = __builtin_amdgcn_cvt_pkrtz(__builtin_amdgcn_exp2f(s01[2] - m[0]),
                                                 __builtin_amdgcn_exp2f(s01[3] - m[0]));
            *reinterpret_cast<float2*>(&pT_lds[wid][0][l15][4*lg])      = u0.f;
            *reinterpret_cast<float2*>(&pT_lds[wid][0][l15][16 + 4*lg]) = u1.f;
            u0.h[0] = __builtin_amdgcn_cvt_pkrtz(__builtin_amdgcn_exp2f(s10[0] - m[1]),
                                                 __builtin_amdgcn_exp2f(s10[1] - m[1]));
            u0.h[1] = __builtin_amdgcn_cvt_pkrtz(__builtin_amdgcn_exp2f(s10[2] - m[1]),
                                                 __builtin_amdgcn_exp2f(s10[3] - m[1]));
            u1.h[0] = __builtin_amdgcn_cvt_pkrtz(__builtin_amdgcn_exp2f(s11[0] - m[1]),
                                                 __builtin_amdgcn_exp2f(s11[1] - m[1]));
            u1.h[1] = __builtin_amdgcn_cvt_pkrtz(__builtin_amdgcn_exp2f(s11[2] - m[1]),
                                                 __builtin_amdgcn_exp2f(s11[3] - m[1]));
            *reinterpret_cast<float2*>(&pT_lds[wid][1][l15][4*lg])      = u0.f;
            *reinterpret_cast<float2*>(&pT_lds[wid][1][l15][16 + 4*lg]) = u1.f;
        }
        f16x8 pa0 = *reinterpret_cast<const f16x8*>(&pT_lds[wid][0][l15][8*lg]);
        f16x8 pa1 = *reinterpret_cast<const f16x8*>(&pT_lds[wid][1][l15][8*lg]);

        // ---- PV(t): Y^T += gT @ P^T (swizzled g reads from buf[cur]) ----
        const f16* gb = &g_lds[cur][0];
        const int grsw = ((l15 >> 1) & 3) << 3;
        #pragma unroll
        for (int ct = 0; ct < 8; ++ct) {
            f16x8 ga = *reinterpret_cast<const f16x8*>(&gb[(ct*16 + l15)*32 + (lg*8 ^ grsw)]);
            acc[0][ct] = __builtin_amdgcn_mfma_f32_16x16x32_f16(ga, pa0, acc[0][ct], 0, 0, 0);
            acc[1][ct] = __builtin_amdgcn_mfma_f32_16x16x32_f16(ga, pa1, acc[1][ct], 0, 0, 0);
        }
        accl[0] = __builtin_amdgcn_mfma_f32_16x16x32_f16(onesA, pa0, accl[0], 0, 0, 0);
        accl[1] = __builtin_amdgcn_mfma_f32_16x16x32_f16(onesA, pa1, accl[1], 0, 0, 0);

        // ---- stage tile t+2 into buf[cur] (both barriers uniform, skipped at tail) ----
        if (have2) {
            __syncthreads();   // all waves done reading buf[cur] g / buf[nxt] phi
            *reinterpret_cast<f16x8*>(&ph_lds[cur][prow*128 + pc0]) = pv0;
            *reinterpret_cast<f16x8*>(&ph_lds[cur][prow*128 + pc1]) = pv1;
            *reinterpret_cast<f16x8*>(&g_lds[cur][grow*32 + gc0])   = gv0;
            *reinterpret_cast<f16x8*>(&g_lds[cur][grow*32 + gc1])   = gv1;
            __syncthreads();   // tile t+2 visible before iter t+1's QK(t+2)
        }

        // ---- rotate S state ----
        s00 = n00; s01 = n01; s10 = n10; s11 = n11;
    }

    // ---- store partials: pacc[bs][ci][n] ----
    #pragma unroll
    for (int qt = 0; qt < 2; ++qt) {
        float* pb = pacc + (size_t)(b*SEG + seg) * CI * NN + qw + qt*16 + l15;
        #pragma unroll
        for (int ct = 0; ct < 8; ++ct)
            #pragma unroll
            for (int r = 0; r < 4; ++r)
                pb[(size_t)(ct*16 + lg*4 + r) * NN] = acc[qt][ct][r];
    }

    if (lg == 0) {
        #pragma unroll
        for (int qt = 0; qt < 2; ++qt) {
            float* mlb = pml + ((size_t)(b*SEG + seg) * NN + qw + qt*16 + l15) * 2;
            mlb[0] = m[qt];
            mlb[1] = accl[qt][0];
        }
    }
}

// ---------------- kernel 3: merge split-KV partials -> yh (f16 [pos][ci]) -----------
__global__ __launch_bounds__(256) void combine_kernel(
    const float* __restrict__ pacc, const float* __restrict__ pml,
    f16* __restrict__ yh)
{
    const int qL = threadIdx.x & 31;
    const int cg = threadIdx.x >> 5;          // 0..7, 16 ci each
    const int q  = blockIdx.x * 32 + qL;
    const int b  = blockIdx.y;

    float mv[SEG], lv[SEG];
    #pragma unroll
    for (int s = 0; s < SEG; ++s) {
        const float* p = pml + ((size_t)(b*SEG + s) * NN + q) * 2;
        mv[s] = p[0];
        lv[s] = p[1];
    }
    float M = mv[0];
    #pragma unroll
    for (int s = 1; s < SEG; ++s) M = fmaxf(M, mv[s]);
    float wsum = 0.f, w[SEG];
    #pragma unroll
    for (int s = 0; s < SEG; ++s) {
        w[s] = __builtin_amdgcn_exp2f(mv[s] - M);
        wsum = fmaf(w[s], lv[s], wsum);
    }
    const float inv = 1.0f / wsum;

    const int c0 = cg * 16;
    float o[16];
    #pragma unroll
    for (int i = 0; i < 16; ++i) o[i] = 0.f;
    for (int s = 0; s < SEG; ++s) {
        const float* pb = pacc + ((size_t)(b*SEG + s) * CI + c0) * NN + q;
        #pragma unroll
        for (int i = 0; i < 16; ++i)
            o[i] = fmaf(w[s], pb[(size_t)i * NN], o[i]);
    }
    f16 oh[16];
    #pragma unroll
    for (int i = 0; i < 16; ++i) oh[i] = (f16)(o[i] * inv);
    f16* yo = yh + ((size_t)b * NN + q) * CI + c0;
    *reinterpret_cast<f16x8*>(yo)     = *reinterpret_cast<f16x8*>(&oh[0]);
    *reinterpret_cast<f16x8*>(yo + 8) = *reinterpret_cast<f16x8*>(&oh[8]);
}

// ---------------- kernel 4: out GEMM (MFMA) + BN + residual ----------------
__global__ __launch_bounds__(256) void out_gemm(
    const float* __restrict__ x, const f16* __restrict__ yh, const f16* __restrict__ WoT,
    const float* __restrict__ bnsc, const float* __restrict__ bnsh, float* __restrict__ out)
{
    const int tid = threadIdx.x;
    const int wid = tid >> 6, lane = tid & 63;
    const int l15 = lane & 15, lg = lane >> 4;
    const int p0 = blockIdx.x * 16;
    const int nq = wid;

    f32x4 acc[4];
    #pragma unroll
    for (int t = 0; t < 4; ++t) acc[t] = (f32x4){0.f,0.f,0.f,0.f};

    const f16* ya = yh + (size_t)(p0 + l15)*CI + lg*8;
    const f16* wb = WoT + (size_t)(nq*64 + l15)*CI + lg*8;
    #pragma unroll
    for (int kk = 0; kk < 4; ++kk) {
        f16x8 a = *reinterpret_cast<const f16x8*>(ya + kk*32);
        #pragma unroll
        for (int t = 0; t < 4; ++t) {
            f16x8 bfr = *reinterpret_cast<const f16x8*>(wb + (size_t)t*16*CI + kk*32);
            acc[t] = __builtin_amdgcn_mfma_f32_16x16x32_f16(a, bfr, acc[t], 0, 0, 0);
        }
    }

    #pragma unroll
    for (int t = 0; t < 4; ++t) {
        const int ci = nq*64 + t*16 + l15;
        const float sc = bnsc[ci], sh = bnsh[ci];
        #pragma unroll
        for (int r = 0; r < 4; ++r) {
            const size_t idx = (size_t)(p0 + lg*4 + r)*CC + ci;
            out[idx] = x[idx] + fmaf(sc, acc[t][r], sh);
        }
    }
}

extern "C" void kernel_launch(void* const* d_in, const int* in_sizes, int n_in,
                              void* d_out, int out_size, void* d_ws, size_t ws_size,
                              hipStream_t stream)
{
    const float* x     = (const float*)d_in[0];
    const float* Wg    = (const float*)d_in[1];
    const float* bg    = (const float*)d_in[2];
    const float* Wt    = (const float*)d_in[3];
    const float* bt    = (const float*)d_in[4];
    const float* Wp    = (const float*)d_in[5];
    const float* bp    = (const float*)d_in[6];
    const float* Wo    = (const float*)d_in[7];
    const float* bo    = (const float*)d_in[8];
    const float* gamma = (const float*)d_in[9];
    const float* beta  = (const float*)d_in[10];
    const float* mmean = (const float*)d_in[11];
    const float* mvar  = (const float*)d_in[12];
    float* out = (float*)d_out;

    const size_t PB = (size_t)BB * NN * CI;                 // 1,605,632
    f16*   th   = (f16*)d_ws;                               // 3.2 MB
    f16*   ph   = th + PB;                                  // 3.2 MB
    f16*   gT   = ph + PB;                                  // 3.2 MB (tiled layout)
    float* pacc = (float*)(gT + PB);                        // 45 MB [bs][ci][n]
    float* pml  = pacc + (size_t)BB * SEG * NN * CI;        // 0.7 MB
    f16*   yh   = (f16*)(pml + (size_t)BB * SEG * NN * 2);  // 3.2 MB
    f16*   WallT= yh + PB;                                  // 197 KB
    f16*   WoT  = WallT + 384*256;                          // 66 KB
    float* ball = (float*)(WoT + 256*CI);                   // 1.5 KB
    float* bnsc = ball + 384;
    float* bnsh = bnsc + 256;

    prep_kernel<<<516, 256, 0, stream>>>(Wg, Wt, Wp, Wo, bg, bt, bp, bo,
                                         gamma, beta, mmean, mvar,
                                         WallT, WoT, ball, bnsc, bnsh);
    proj_gemm<<<BB * NN / 16, 256, 0, stream>>>(x, WallT, ball, th, ph, gT);
    attn_kernel<<<dim3(NN / 128, SEG, BB), 256, 0, stream>>>(th, ph, gT, pacc, pml);
    combine_kernel<<<dim3(NN / 32, BB), 256, 0, stream>>>(pacc, pml, yh);
    out_gemm<<<BB * NN / 16, 256, 0, stream>>>(x, yh, WoT, bnsc, bnsh, out);
}

// Round 10
// 127.876 us; speedup vs baseline: 1.2177x; 1.2177x over previous
//
#include <hip/hip_runtime.h>

#define BB 2
#define NN 6272
#define CC 256
#define CI 128
#define SEG 7
#define KVSEG (NN / SEG)          // 896 kv per segment, 28 tiles of 32
#define NIT (KVSEG / 32)
#define LOG2E 1.44269504088896f
#define THR 12.0f                 // defer-max threshold (log2 domain), P <= 4096 fits f16

typedef _Float16 f16;
typedef __attribute__((ext_vector_type(2))) __fp16 fp16v2;   // cvt_pkrtz native type
typedef __attribute__((ext_vector_type(8))) _Float16 f16x8;
typedef __attribute__((ext_vector_type(4))) float f32x4;

// ---------------- kernel 0: weight prep (once, ~3us) ----------------
__global__ __launch_bounds__(256) void prep_kernel(
    const float* __restrict__ Wg, const float* __restrict__ Wt, const float* __restrict__ Wp,
    const float* __restrict__ Wo, const float* __restrict__ bg, const float* __restrict__ bt,
    const float* __restrict__ bp, const float* __restrict__ bo,
    const float* __restrict__ gamma, const float* __restrict__ beta,
    const float* __restrict__ mmean, const float* __restrict__ mvar,
    f16* __restrict__ WallT, f16* __restrict__ WoT,
    float* __restrict__ ball, float* __restrict__ bnsc, float* __restrict__ bnsh)
{
    const int idx = blockIdx.x * 256 + threadIdx.x;
    if (idx < 384*256) {
        const int j = idx >> 8, k = idx & 255;
        float v;
        if (j < 128)      v = Wg[k*CI + j];
        else if (j < 256) v = Wt[k*CI + (j-128)] * LOG2E;
        else              v = Wp[k*CI + (j-256)];
        WallT[j*256 + k] = (f16)v;
    } else if (idx < 384*256 + 256*128) {
        const int i2 = idx - 384*256;
        const int ci = i2 >> 7, k = i2 & 127;
        WoT[ci*CI + k] = (f16)Wo[k*CC + ci];
    } else {
        const int i3 = idx - (384*256 + 256*128);
        if (i3 < 384) {
            float v;
            if (i3 < 128)      v = bg[i3];
            else if (i3 < 256) v = bt[i3-128] * LOG2E;
            else               v = bp[i3-256];
            ball[i3] = v;
        } else if (i3 < 640) {
            const int c = i3 - 384;
            bnsc[c] = gamma[c] * rsqrtf(mvar[c] + 1e-3f);
        } else if (i3 < 896) {
            const int c = i3 - 640;
            float sc = gamma[c] * rsqrtf(mvar[c] + 1e-3f);
            bnsh[c] = beta[c] + sc * (bo[c] - mmean[c]);
        }
    }
}

// ---------------- kernel 1: fused projection GEMM (MFMA) ----------------
// gT tiled: [b][n/32][ci][32]  (32-kv tiles, contiguous 8KB per tile)
__global__ __launch_bounds__(256) void proj_gemm(
    const float* __restrict__ x, const f16* __restrict__ WallT, const float* __restrict__ ball,
    f16* __restrict__ th, f16* __restrict__ ph, f16* __restrict__ gT)
{
    __shared__ __align__(16) f16 xls[16*264];
    __shared__ __align__(16) f16 gls[128*24];

    const int tid = threadIdx.x;
    const int wid = tid >> 6, lane = tid & 63;
    const int l15 = lane & 15, lg = lane >> 4;
    const int p0 = blockIdx.x * 16;
    const int nq = wid;

    {   // stage x tile 16x256 -> f16 LDS
        const int row = tid >> 4, seg = (tid & 15) * 16;
        const float* xsrc = x + (size_t)(p0 + row) * CC + seg;
        f16 buf[16];
        #pragma unroll
        for (int i = 0; i < 4; ++i) {
            float4 v = *reinterpret_cast<const float4*>(xsrc + 4*i);
            buf[4*i+0]=(f16)v.x; buf[4*i+1]=(f16)v.y; buf[4*i+2]=(f16)v.z; buf[4*i+3]=(f16)v.w;
        }
        *reinterpret_cast<f16x8*>(&xls[row*264 + seg])     = *reinterpret_cast<f16x8*>(&buf[0]);
        *reinterpret_cast<f16x8*>(&xls[row*264 + seg + 8]) = *reinterpret_cast<f16x8*>(&buf[8]);
    }
    __syncthreads();

    f32x4 acc[6];
    #pragma unroll
    for (int t = 0; t < 6; ++t) acc[t] = (f32x4){0.f,0.f,0.f,0.f};

    const f16* wbase = WallT + (size_t)(nq*96 + l15)*256 + lg*8;
    for (int kk = 0; kk < 8; ++kk) {
        f16x8 a = *reinterpret_cast<const f16x8*>(&xls[l15*264 + kk*32 + lg*8]);
        #pragma unroll
        for (int t = 0; t < 6; ++t) {
            f16x8 bfr = *reinterpret_cast<const f16x8*>(wbase + (size_t)t*16*256 + kk*32);
            acc[t] = __builtin_amdgcn_mfma_f32_16x16x32_f16(a, bfr, acc[t], 0, 0, 0);
        }
    }

    const int bidx = (p0 >= NN) ? 1 : 0;
    const int n0 = p0 - bidx * NN;
    const int prow = lg * 4;

    #pragma unroll
    for (int t = 0; t < 6; ++t) {
        const int j0 = nq*96 + t*16;          // + l15 per lane
        const float bv = ball[j0 + l15];
        if (j0 < 128) {          // g -> LDS transpose
            #pragma unroll
            for (int r = 0; r < 4; ++r)
                gls[(j0 + l15)*24 + prow + r] = (f16)(acc[t][r] + bv);
        } else if (j0 < 256) {   // theta (pre-scaled)
            f16* dst = th + (size_t)(p0 + prow)*CI + (j0 - 128) + l15;
            #pragma unroll
            for (int r = 0; r < 4; ++r)
                dst[(size_t)r*CI] = (f16)(acc[t][r] + bv);
        } else {                 // phi
            f16* dst = ph + (size_t)(p0 + prow)*CI + (j0 - 256) + l15;
            #pragma unroll
            for (int r = 0; r < 4; ++r)
                dst[(size_t)r*CI] = (f16)(acc[t][r] + bv);
        }
    }
    __syncthreads();
    {   // tiled gT store: [b][n/32][ci][32]
        const int ci = tid >> 1, part = tid & 1;
        f16x8 v = *reinterpret_cast<const f16x8*>(&gls[ci*24 + part*8]);
        f16* gdst = gT + ((size_t)bidx*(NN/32) + (n0 >> 5))*(CI*32)
                       + ci*32 + (n0 & 16) + part*8;
        *reinterpret_cast<f16x8*>(gdst) = v;
    }
}

// ---------------- kernel 2: split-KV flash attention, 1-tile software pipeline -------
// grid (NN/128, SEG, BB); 4 waves/block; wave owns 32 q rows. KV tile = 32.
// S(t) held in registers across iterations. Loop body:
//   issue loads(t+2) -> QK(t+1) MFMAs (results needed next iter: infinite slack)
//   -> softmax(t) (VALU, overlaps QK retire) -> pa(t) -> PV(t)
//   -> [barrier; stage tile t+2 -> buf[t&1]; barrier]   (skipped for last 2 iters)
// launch_bounds(256,2): unified reg budget 256 -- pipeline state (~175 regs incl.
// AGPR acc) MUST fit without spill (R9 spilled at the (256,3) 170-reg cap:
// WRITE_SIZE +20MB scratch, MfmaUtil 25->15.6).
__global__ __launch_bounds__(256, 2) void attn_kernel(
    const f16* __restrict__ th, const f16* __restrict__ ph,
    const f16* __restrict__ gT, float* __restrict__ pacc, float* __restrict__ pml)
{
    __shared__ __align__(16) f16 ph_lds[2][32 * 128];  // dbuf [kv][c], swizzled
    __shared__ __align__(16) f16 g_lds[2][128 * 32];   // dbuf [ci][kv], swizzled
    __shared__ __align__(16) f16 pT_lds[4][2][16][40]; // per-wave [qt][q][kv+pad]

    const int b   = blockIdx.z;
    const int seg = blockIdx.y;
    const int tid = threadIdx.x;
    const int wid = tid >> 6;
    const int lane = tid & 63;
    const int l15 = lane & 15;
    const int lg  = lane >> 4;
    const int qw  = blockIdx.x * 128 + wid * 32;

    const f16* thb = th + (size_t)b * NN * CI;
    const f16* phb = ph + (size_t)b * NN * CI;
    const f16* gTb = gT + (size_t)b * (NN/32) * (CI*32);

    // persistent theta B-frags: 2 q-tiles x 4 k-frags
    f16x8 bf[2][4];
    #pragma unroll
    for (int qt = 0; qt < 2; ++qt) {
        const f16* trow = thb + (size_t)(qw + qt*16 + l15) * CI + lg * 8;
        #pragma unroll
        for (int kk = 0; kk < 4; ++kk)
            bf[qt][kk] = *reinterpret_cast<const f16x8*>(trow + kk * 32);
    }

    f32x4 acc[2][8];              // Y^T: per q-tile, 8 ci-tiles, col=q
    f32x4 accl[2];                // row-sums (ones trick)
    float m[2] = {-INFINITY, -INFINITY};
    #pragma unroll
    for (int qt = 0; qt < 2; ++qt) {
        #pragma unroll
        for (int ct = 0; ct < 8; ++ct) acc[qt][ct] = (f32x4){0.f,0.f,0.f,0.f};
        accl[qt] = (f32x4){0.f,0.f,0.f,0.f};
    }

    const f16x8 onesA = {(f16)1,(f16)1,(f16)1,(f16)1,(f16)1,(f16)1,(f16)1,(f16)1};

    // phi staging: 32 rows x 128 c, XOR-swizzled
    const int prow = tid >> 3, pcol = (tid & 7) * 16;
    const int pswz = (prow & 7) << 3;
    const int pc0 = pcol ^ pswz, pc1 = (pcol + 8) ^ pswz;
    // g staging: 128 rows x 32 kv, XOR-swizzled; source tile contiguous 8KB
    const int grow = tid >> 1, gcs = (tid & 1) * 16;
    const int gswz = ((grow >> 1) & 3) << 3;
    const int gc0 = gcs ^ gswz, gc1 = (gcs + 8) ^ gswz;

    const int kv_base = seg * KVSEG;
    const int t0 = kv_base >> 5;            // first g tile index
    const int xsw = (l15 & 7) << 3;

    // ---- prologue: stage tile 0 ----
    {
        const f16* ps = phb + (size_t)(kv_base + prow) * CI + pcol;
        f16x8 a = *reinterpret_cast<const f16x8*>(ps);
        f16x8 c = *reinterpret_cast<const f16x8*>(ps + 8);
        const f16* gs = gTb + (size_t)t0 * (CI*32) + tid * 16;
        f16x8 g0 = *reinterpret_cast<const f16x8*>(gs);
        f16x8 g1 = *reinterpret_cast<const f16x8*>(gs + 8);
        *reinterpret_cast<f16x8*>(&ph_lds[0][prow*128 + pc0]) = a;
        *reinterpret_cast<f16x8*>(&ph_lds[0][prow*128 + pc1]) = c;
        *reinterpret_cast<f16x8*>(&g_lds[0][grow*32 + gc0])   = g0;
        *reinterpret_cast<f16x8*>(&g_lds[0][grow*32 + gc1])   = g1;
    }
    __syncthreads();

    // ---- prologue: issue tile-1 loads, QK(0), stage tile 1 ----
    f32x4 s00, s01, s10, s11;
    {
        const f16* ps = phb + (size_t)(kv_base + 32 + prow) * CI + pcol;
        f16x8 pv0 = *reinterpret_cast<const f16x8*>(ps);
        f16x8 pv1 = *reinterpret_cast<const f16x8*>(ps + 8);
        const f16* gs = gTb + (size_t)(t0 + 1) * (CI*32) + tid * 16;
        f16x8 gv0 = *reinterpret_cast<const f16x8*>(gs);
        f16x8 gv1 = *reinterpret_cast<const f16x8*>(gs + 8);

        s00 = (f32x4){0.f,0.f,0.f,0.f}; s01 = (f32x4){0.f,0.f,0.f,0.f};
        s10 = (f32x4){0.f,0.f,0.f,0.f}; s11 = (f32x4){0.f,0.f,0.f,0.f};
        #pragma unroll
        for (int kk = 0; kk < 4; ++kk) {
            const int coff = (kk*32 + lg*8) ^ xsw;
            f16x8 a0 = *reinterpret_cast<const f16x8*>(&ph_lds[0][l15*128 + coff]);
            f16x8 a1 = *reinterpret_cast<const f16x8*>(&ph_lds[0][(16 + l15)*128 + coff]);
            s00 = __builtin_amdgcn_mfma_f32_16x16x32_f16(a0, bf[0][kk], s00, 0, 0, 0);
            s01 = __builtin_amdgcn_mfma_f32_16x16x32_f16(a1, bf[0][kk], s01, 0, 0, 0);
            s10 = __builtin_amdgcn_mfma_f32_16x16x32_f16(a0, bf[1][kk], s10, 0, 0, 0);
            s11 = __builtin_amdgcn_mfma_f32_16x16x32_f16(a1, bf[1][kk], s11, 0, 0, 0);
        }
        *reinterpret_cast<f16x8*>(&ph_lds[1][prow*128 + pc0]) = pv0;
        *reinterpret_cast<f16x8*>(&ph_lds[1][prow*128 + pc1]) = pv1;
        *reinterpret_cast<f16x8*>(&g_lds[1][grow*32 + gc0])   = gv0;
        *reinterpret_cast<f16x8*>(&g_lds[1][grow*32 + gc1])   = gv1;
    }
    __syncthreads();

    #pragma unroll 1
    for (int it = 0; it < NIT; ++it) {
        const int cur = it & 1, nxt = cur ^ 1;
        const bool have2 = (it + 2 < NIT);
        const int it2 = have2 ? (it + 2) : (NIT - 1);

        // ---- issue tile t+2 loads (land during this iteration's compute) ----
        const f16* ps = phb + (size_t)(kv_base + it2*32 + prow) * CI + pcol;
        f16x8 pv0 = *reinterpret_cast<const f16x8*>(ps);
        f16x8 pv1 = *reinterpret_cast<const f16x8*>(ps + 8);
        const f16* gs = gTb + (size_t)(t0 + it2) * (CI*32) + tid * 16;
        f16x8 gv0 = *reinterpret_cast<const f16x8*>(gs);
        f16x8 gv1 = *reinterpret_cast<const f16x8*>(gs + 8);

        // ---- QK(t+1) from buf[nxt] (results needed next iter -> full slack) ----
        f32x4 n00 = (f32x4){0.f,0.f,0.f,0.f}, n01 = (f32x4){0.f,0.f,0.f,0.f};
        f32x4 n10 = (f32x4){0.f,0.f,0.f,0.f}, n11 = (f32x4){0.f,0.f,0.f,0.f};
        if (it + 1 < NIT) {
            const f16* cb = &ph_lds[nxt][0];
            #pragma unroll
            for (int kk = 0; kk < 4; ++kk) {
                const int coff = (kk*32 + lg*8) ^ xsw;
                f16x8 a0 = *reinterpret_cast<const f16x8*>(&cb[l15*128 + coff]);
                f16x8 a1 = *reinterpret_cast<const f16x8*>(&cb[(16 + l15)*128 + coff]);
                n00 = __builtin_amdgcn_mfma_f32_16x16x32_f16(a0, bf[0][kk], n00, 0, 0, 0);
                n01 = __builtin_amdgcn_mfma_f32_16x16x32_f16(a1, bf[0][kk], n01, 0, 0, 0);
                n10 = __builtin_amdgcn_mfma_f32_16x16x32_f16(a0, bf[1][kk], n10, 0, 0, 0);
                n11 = __builtin_amdgcn_mfma_f32_16x16x32_f16(a1, bf[1][kk], n11, 0, 0, 0);
            }
        }

        // ---- softmax(t) on held s-regs (VALU; overlaps QK retire) ----
        float tm0 = fmaxf(fmaxf(fmaxf(s00[0], s00[1]), fmaxf(s00[2], s00[3])),
                          fmaxf(fmaxf(s01[0], s01[1]), fmaxf(s01[2], s01[3])));
        float tm1 = fmaxf(fmaxf(fmaxf(s10[0], s10[1]), fmaxf(s10[2], s10[3])),
                          fmaxf(fmaxf(s11[0], s11[1]), fmaxf(s11[2], s11[3])));
        tm0 = fmaxf(tm0, __shfl_xor(tm0, 16));
        tm0 = fmaxf(tm0, __shfl_xor(tm0, 32));
        tm1 = fmaxf(tm1, __shfl_xor(tm1, 16));
        tm1 = fmaxf(tm1, __shfl_xor(tm1, 32));
        if (__any((tm0 > m[0] + THR) || (tm1 > m[1] + THR))) {
            float nm0 = fmaxf(m[0], tm0), nm1 = fmaxf(m[1], tm1);
            float sc0 = __builtin_amdgcn_exp2f(m[0] - nm0);
            float sc1 = __builtin_amdgcn_exp2f(m[1] - nm1);
            m[0] = nm0; m[1] = nm1;
            #pragma unroll
            for (int ct = 0; ct < 8; ++ct) {
                acc[0][ct][0] *= sc0; acc[0][ct][1] *= sc0; acc[0][ct][2] *= sc0; acc[0][ct][3] *= sc0;
                acc[1][ct][0] *= sc1; acc[1][ct][1] *= sc1; acc[1][ct][2] *= sc1; acc[1][ct][3] *= sc1;
            }
            accl[0][0] *= sc0; accl[0][1] *= sc0; accl[0][2] *= sc0; accl[0][3] *= sc0;
            accl[1][0] *= sc1; accl[1][1] *= sc1; accl[1][2] *= sc1; accl[1][3] *= sc1;
        }

        // ---- P(t) = exp2(s - m), pack f16, exchange via per-wave LDS ----
        {
            union { fp16v2 h[2]; float2 f; } u0, u1;
            u0.h[0] = __builtin_amdgcn_cvt_pkrtz(__builtin_amdgcn_exp2f(s00[0] - m[0]),
                                                 __builtin_amdgcn_exp2f(s00[1] - m[0]));
            u0.h[1] = __builtin_amdgcn_cvt_pkrtz(__builtin_amdgcn_exp2f(s00[2] - m[0]),
                                                 __builtin_amdgcn_exp2f(s00[3] - m[0]));
            u1.h[0] = __builtin_amdgcn_cvt_pkrtz(__builtin_amdgcn_exp2f(s01[0] - m[0]),
                                                 __builtin_amdgcn_exp2f(s01[1] - m[0]));
            u1.h[1] = __builtin_amdgcn_cvt_pkrtz(__builtin_amdgcn_exp2f(s01[2] - m[0]),
                                                 __builtin_amdgcn_exp2f(s01[3] - m[0]));
            *reinterpret_cast<float2*>(&pT_lds[wid][0][l15][4*lg])      = u0.f;
            *reinterpret_cast<float2*>(&pT_lds[wid][0][l15][16 + 4*lg]) = u1.f;
            u0.h[0] = __builtin_amdgcn_cvt_pkrtz(__builtin_amdgcn_exp2f(s10[0] - m[1]),
                                                 __builtin_amdgcn_exp2f(s10[1] - m[1]));
            u0.h[1] = __builtin_amdgcn_cvt_pkrtz(__builtin_amdgcn_exp2f(s10[2] - m[1]),
                                                 __builtin_amdgcn_exp2f(s10[3] - m[1]));
            u1.h[0] = __builtin_amdgcn_cvt_pkrtz(__builtin_amdgcn_exp2f(s11[0] - m[1]),
                                                 __builtin_amdgcn_exp2f(s11[1] - m[1]));
            u1.h[1] = __builtin_amdgcn_cvt_pkrtz(__builtin_amdgcn_exp2f(s11[2] - m[1]),
                                                 __builtin_amdgcn_exp2f(s11[3] - m[1]));
            *reinterpret_cast<float2*>(&pT_lds[wid][1][l15][4*lg])      = u0.f;
            *reinterpret_cast<float2*>(&pT_lds[wid][1][l15][16 + 4*lg]) = u1.f;
        }
        f16x8 pa0 = *reinterpret_cast<const f16x8*>(&pT_lds[wid][0][l15][8*lg]);
        f16x8 pa1 = *reinterpret_cast<const f16x8*>(&pT_lds[wid][1][l15][8*lg]);

        // ---- PV(t): Y^T += gT @ P^T (swizzled g reads from buf[cur]) ----
        const f16* gb = &g_lds[cur][0];
        const int grsw = ((l15 >> 1) & 3) << 3;
        #pragma unroll
        for (int ct = 0; ct < 8; ++ct) {
            f16x8 ga = *reinterpret_cast<const f16x8*>(&gb[(ct*16 + l15)*32 + (lg*8 ^ grsw)]);
            acc[0][ct] = __builtin_amdgcn_mfma_f32_16x16x32_f16(ga, pa0, acc[0][ct], 0, 0, 0);
            acc[1][ct] = __builtin_amdgcn_mfma_f32_16x16x32_f16(ga, pa1, acc[1][ct], 0, 0, 0);
        }
        accl[0] = __builtin_amdgcn_mfma_f32_16x16x32_f16(onesA, pa0, accl[0], 0, 0, 0);
        accl[1] = __builtin_amdgcn_mfma_f32_16x16x32_f16(onesA, pa1, accl[1], 0, 0, 0);

        // ---- stage tile t+2 into buf[cur] (both barriers uniform, skipped at tail) ----
        if (have2) {
            __syncthreads();   // all waves done reading buf[cur] g / buf[nxt] phi
            *reinterpret_cast<f16x8*>(&ph_lds[cur][prow*128 + pc0]) = pv0;
            *reinterpret_cast<f16x8*>(&ph_lds[cur][prow*128 + pc1]) = pv1;
            *reinterpret_cast<f16x8*>(&g_lds[cur][grow*32 + gc0])   = gv0;
            *reinterpret_cast<f16x8*>(&g_lds[cur][grow*32 + gc1])   = gv1;
            __syncthreads();   // tile t+2 visible before iter t+1's QK(t+2)
        }

        // ---- rotate S state ----
        s00 = n00; s01 = n01; s10 = n10; s11 = n11;
    }

    // ---- store partials: pacc[bs][ci][n] ----
    #pragma unroll
    for (int qt = 0; qt < 2; ++qt) {
        float* pb = pacc + (size_t)(b*SEG + seg) * CI * NN + qw + qt*16 + l15;
        #pragma unroll
        for (int ct = 0; ct < 8; ++ct)
            #pragma unroll
            for (int r = 0; r < 4; ++r)
                pb[(size_t)(ct*16 + lg*4 + r) * NN] = acc[qt][ct][r];
    }

    if (lg == 0) {
        #pragma unroll
        for (int qt = 0; qt < 2; ++qt) {
            float* mlb = pml + ((size_t)(b*SEG + seg) * NN + qw + qt*16 + l15) * 2;
            mlb[0] = m[qt];
            mlb[1] = accl[qt][0];
        }
    }
}

// ---------------- kernel 3: merge split-KV partials -> yh (f16 [pos][ci]) -----------
__global__ __launch_bounds__(256) void combine_kernel(
    const float* __restrict__ pacc, const float* __restrict__ pml,
    f16* __restrict__ yh)
{
    const int qL = threadIdx.x & 31;
    const int cg = threadIdx.x >> 5;          // 0..7, 16 ci each
    const int q  = blockIdx.x * 32 + qL;
    const int b  = blockIdx.y;

    float mv[SEG], lv[SEG];
    #pragma unroll
    for (int s = 0; s < SEG; ++s) {
        const float* p = pml + ((size_t)(b*SEG + s) * NN + q) * 2;
        mv[s] = p[0];
        lv[s] = p[1];
    }
    float M = mv[0];
    #pragma unroll
    for (int s = 1; s < SEG; ++s) M = fmaxf(M, mv[s]);
    float wsum = 0.f, w[SEG];
    #pragma unroll
    for (int s = 0; s < SEG; ++s) {
        w[s] = __builtin_amdgcn_exp2f(mv[s] - M);
        wsum = fmaf(w[s], lv[s], wsum);
    }
    const float inv = 1.0f / wsum;

    const int c0 = cg * 16;
    float o[16];
    #pragma unroll
    for (int i = 0; i < 16; ++i) o[i] = 0.f;
    for (int s = 0; s < SEG; ++s) {
        const float* pb = pacc + ((size_t)(b*SEG + s) * CI + c0) * NN + q;
        #pragma unroll
        for (int i = 0; i < 16; ++i)
            o[i] = fmaf(w[s], pb[(size_t)i * NN], o[i]);
    }
    f16 oh[16];
    #pragma unroll
    for (int i = 0; i < 16; ++i) oh[i] = (f16)(o[i] * inv);
    f16* yo = yh + ((size_t)b * NN + q) * CI + c0;
    *reinterpret_cast<f16x8*>(yo)     = *reinterpret_cast<f16x8*>(&oh[0]);
    *reinterpret_cast<f16x8*>(yo + 8) = *reinterpret_cast<f16x8*>(&oh[8]);
}

// ---------------- kernel 4: out GEMM (MFMA) + BN + residual ----------------
__global__ __launch_bounds__(256) void out_gemm(
    const float* __restrict__ x, const f16* __restrict__ yh, const f16* __restrict__ WoT,
    const float* __restrict__ bnsc, const float* __restrict__ bnsh, float* __restrict__ out)
{
    const int tid = threadIdx.x;
    const int wid = tid >> 6, lane = tid & 63;
    const int l15 = lane & 15, lg = lane >> 4;
    const int p0 = blockIdx.x * 16;
    const int nq = wid;

    f32x4 acc[4];
    #pragma unroll
    for (int t = 0; t < 4; ++t) acc[t] = (f32x4){0.f,0.f,0.f,0.f};

    const f16* ya = yh + (size_t)(p0 + l15)*CI + lg*8;
    const f16* wb = WoT + (size_t)(nq*64 + l15)*CI + lg*8;
    #pragma unroll
    for (int kk = 0; kk < 4; ++kk) {
        f16x8 a = *reinterpret_cast<const f16x8*>(ya + kk*32);
        #pragma unroll
        for (int t = 0; t < 4; ++t) {
            f16x8 bfr = *reinterpret_cast<const f16x8*>(wb + (size_t)t*16*CI + kk*32);
            acc[t] = __builtin_amdgcn_mfma_f32_16x16x32_f16(a, bfr, acc[t], 0, 0, 0);
        }
    }

    #pragma unroll
    for (int t = 0; t < 4; ++t) {
        const int ci = nq*64 + t*16 + l15;
        const float sc = bnsc[ci], sh = bnsh[ci];
        #pragma unroll
        for (int r = 0; r < 4; ++r) {
            const size_t idx = (size_t)(p0 + lg*4 + r)*CC + ci;
            out[idx] = x[idx] + fmaf(sc, acc[t][r], sh);
        }
    }
}

extern "C" void kernel_launch(void* const* d_in, const int* in_sizes, int n_in,
                              void* d_out, int out_size, void* d_ws, size_t ws_size,
                              hipStream_t stream)
{
    const float* x     = (const float*)d_in[0];
    const float* Wg    = (const float*)d_in[1];
    const float* bg    = (const float*)d_in[2];
    const float* Wt    = (const float*)d_in[3];
    const float* bt    = (const float*)d_in[4];
    const float* Wp    = (const float*)d_in[5];
    const float* bp    = (const float*)d_in[6];
    const float* Wo    = (const float*)d_in[7];
    const float* bo    = (const float*)d_in[8];
    const float* gamma = (const float*)d_in[9];
    const float* beta  = (const float*)d_in[10];
    const float* mmean = (const float*)d_in[11];
    const float* mvar  = (const float*)d_in[12];
    float* out = (float*)d_out;

    const size_t PB = (size_t)BB * NN * CI;                 // 1,605,632
    f16*   th   = (f16*)d_ws;                               // 3.2 MB
    f16*   ph   = th + PB;                                  // 3.2 MB
    f16*   gT   = ph + PB;                                  // 3.2 MB (tiled layout)
    float* pacc = (float*)(gT + PB);                        // 45 MB [bs][ci][n]
    float* pml  = pacc + (size_t)BB * SEG * NN * CI;        // 0.7 MB
    f16*   yh   = (f16*)(pml + (size_t)BB * SEG * NN * 2);  // 3.2 MB
    f16*   WallT= yh + PB;                                  // 197 KB
    f16*   WoT  = WallT + 384*256;                          // 66 KB
    float* ball = (float*)(WoT + 256*CI);                   // 1.5 KB
    float* bnsc = ball + 384;
    float* bnsh = bnsc + 256;

    prep_kernel<<<516, 256, 0, stream>>>(Wg, Wt, Wp, Wo, bg, bt, bp, bo,
                                         gamma, beta, mmean, mvar,
                                         WallT, WoT, ball, bnsc, bnsh);
    proj_gemm<<<BB * NN / 16, 256, 0, stream>>>(x, WallT, ball, th, ph, gT);
    attn_kernel<<<dim3(NN / 128, SEG, BB), 256, 0, stream>>>(th, ph, gT, pacc, pml);
    combine_kernel<<<dim3(NN / 32, BB), 256, 0, stream>>>(pacc, pml, yh);
    out_gemm<<<BB * NN / 16, 256, 0, stream>>>(x, yh, WoT, bnsc, bnsh, out);
}

// Round 11
// 122.777 us; speedup vs baseline: 1.2683x; 1.0415x over previous
//
#include <hip/hip_runtime.h>

#define BB 2
#define NN 6272
#define CC 256
#define CI 128
#define SEG 14
#define KVSEG (NN / SEG)          // 448 kv per segment, 14 tiles of 32
#define NIT (KVSEG / 32)
#define LOG2E 1.44269504088896f
#define THR 12.0f                 // defer-max threshold (log2 domain), P <= 4096 fits f16

typedef _Float16 f16;
typedef __attribute__((ext_vector_type(2))) __fp16 fp16v2;   // cvt_pkrtz native type
typedef __attribute__((ext_vector_type(8))) _Float16 f16x8;
typedef __attribute__((ext_vector_type(4))) float f32x4;

// ---------------- kernel 0: weight prep (once, ~3us) ----------------
__global__ __launch_bounds__(256) void prep_kernel(
    const float* __restrict__ Wg, const float* __restrict__ Wt, const float* __restrict__ Wp,
    const float* __restrict__ Wo, const float* __restrict__ bg, const float* __restrict__ bt,
    const float* __restrict__ bp, const float* __restrict__ bo,
    const float* __restrict__ gamma, const float* __restrict__ beta,
    const float* __restrict__ mmean, const float* __restrict__ mvar,
    f16* __restrict__ WallT, f16* __restrict__ WoT,
    float* __restrict__ ball, float* __restrict__ bnsc, float* __restrict__ bnsh)
{
    const int idx = blockIdx.x * 256 + threadIdx.x;
    if (idx < 384*256) {
        const int j = idx >> 8, k = idx & 255;
        float v;
        if (j < 128)      v = Wg[k*CI + j];
        else if (j < 256) v = Wt[k*CI + (j-128)] * LOG2E;
        else              v = Wp[k*CI + (j-256)];
        WallT[j*256 + k] = (f16)v;
    } else if (idx < 384*256 + 256*128) {
        const int i2 = idx - 384*256;
        const int ci = i2 >> 7, k = i2 & 127;
        WoT[ci*CI + k] = (f16)Wo[k*CC + ci];
    } else {
        const int i3 = idx - (384*256 + 256*128);
        if (i3 < 384) {
            float v;
            if (i3 < 128)      v = bg[i3];
            else if (i3 < 256) v = bt[i3-128] * LOG2E;
            else               v = bp[i3-256];
            ball[i3] = v;
        } else if (i3 < 640) {
            const int c = i3 - 384;
            bnsc[c] = gamma[c] * rsqrtf(mvar[c] + 1e-3f);
        } else if (i3 < 896) {
            const int c = i3 - 640;
            float sc = gamma[c] * rsqrtf(mvar[c] + 1e-3f);
            bnsh[c] = beta[c] + sc * (bo[c] - mmean[c]);
        }
    }
}

// ---------------- kernel 1: fused projection GEMM (MFMA) ----------------
// gT tiled: [b][n/32][ci][32]  (32-kv tiles, contiguous 8KB per tile)
__global__ __launch_bounds__(256) void proj_gemm(
    const float* __restrict__ x, const f16* __restrict__ WallT, const float* __restrict__ ball,
    f16* __restrict__ th, f16* __restrict__ ph, f16* __restrict__ gT)
{
    __shared__ __align__(16) f16 xls[16*264];
    __shared__ __align__(16) f16 gls[128*24];

    const int tid = threadIdx.x;
    const int wid = tid >> 6, lane = tid & 63;
    const int l15 = lane & 15, lg = lane >> 4;
    const int p0 = blockIdx.x * 16;
    const int nq = wid;

    {   // stage x tile 16x256 -> f16 LDS
        const int row = tid >> 4, seg = (tid & 15) * 16;
        const float* xsrc = x + (size_t)(p0 + row) * CC + seg;
        f16 buf[16];
        #pragma unroll
        for (int i = 0; i < 4; ++i) {
            float4 v = *reinterpret_cast<const float4*>(xsrc + 4*i);
            buf[4*i+0]=(f16)v.x; buf[4*i+1]=(f16)v.y; buf[4*i+2]=(f16)v.z; buf[4*i+3]=(f16)v.w;
        }
        *reinterpret_cast<f16x8*>(&xls[row*264 + seg])     = *reinterpret_cast<f16x8*>(&buf[0]);
        *reinterpret_cast<f16x8*>(&xls[row*264 + seg + 8]) = *reinterpret_cast<f16x8*>(&buf[8]);
    }
    __syncthreads();

    f32x4 acc[6];
    #pragma unroll
    for (int t = 0; t < 6; ++t) acc[t] = (f32x4){0.f,0.f,0.f,0.f};

    const f16* wbase = WallT + (size_t)(nq*96 + l15)*256 + lg*8;
    for (int kk = 0; kk < 8; ++kk) {
        f16x8 a = *reinterpret_cast<const f16x8*>(&xls[l15*264 + kk*32 + lg*8]);
        #pragma unroll
        for (int t = 0; t < 6; ++t) {
            f16x8 bfr = *reinterpret_cast<const f16x8*>(wbase + (size_t)t*16*256 + kk*32);
            acc[t] = __builtin_amdgcn_mfma_f32_16x16x32_f16(a, bfr, acc[t], 0, 0, 0);
        }
    }

    const int bidx = (p0 >= NN) ? 1 : 0;
    const int n0 = p0 - bidx * NN;
    const int prow = lg * 4;

    #pragma unroll
    for (int t = 0; t < 6; ++t) {
        const int j0 = nq*96 + t*16;          // + l15 per lane
        const float bv = ball[j0 + l15];
        if (j0 < 128) {          // g -> LDS transpose
            #pragma unroll
            for (int r = 0; r < 4; ++r)
                gls[(j0 + l15)*24 + prow + r] = (f16)(acc[t][r] + bv);
        } else if (j0 < 256) {   // theta (pre-scaled)
            f16* dst = th + (size_t)(p0 + prow)*CI + (j0 - 128) + l15;
            #pragma unroll
            for (int r = 0; r < 4; ++r)
                dst[(size_t)r*CI] = (f16)(acc[t][r] + bv);
        } else {                 // phi
            f16* dst = ph + (size_t)(p0 + prow)*CI + (j0 - 256) + l15;
            #pragma unroll
            for (int r = 0; r < 4; ++r)
                dst[(size_t)r*CI] = (f16)(acc[t][r] + bv);
        }
    }
    __syncthreads();
    {   // tiled gT store: [b][n/32][ci][32]
        const int ci = tid >> 1, part = tid & 1;
        f16x8 v = *reinterpret_cast<const f16x8*>(&gls[ci*24 + part*8]);
        f16* gdst = gT + ((size_t)bidx*(NN/32) + (n0 >> 5))*(CI*32)
                       + ci*32 + (n0 & 16) + part*8;
        *reinterpret_cast<f16x8*>(gdst) = v;
    }
}

// ---------------- kernel 2: split-KV flash attention (R6 structure, SEG=14) ---------
// grid (NN/128, SEG, BB); 4 waves/block; wave owns 32 q rows. KV tile = 32.
// Single-buffered phi/g LDS tiles, loads issued at top, 2 barriers/iter —
// the best-measured structure (66.3us @ SEG=7). Occupancy lever: SEG=14 ->
// 1372 blocks = 5.4/CU (LDS 26.6KB and VGPR 84 allow ~6 resident).
// Partials stored NORMALIZED (acc/l) as f16: traffic at SEG=14 == fp32@SEG=7.
__global__ __launch_bounds__(256, 3) void attn_kernel(
    const f16* __restrict__ th, const f16* __restrict__ ph,
    const f16* __restrict__ gT, f16* __restrict__ pacc, float* __restrict__ pml)
{
    __shared__ __align__(16) f16 ph_lds[32 * 128];     // [kv][c], swizzled
    __shared__ __align__(16) f16 g_lds[128 * 32];      // [ci][kv], swizzled
    __shared__ __align__(16) f16 pT_lds[4][2][16][40]; // per-wave [qt][q][kv+pad]

    const int b   = blockIdx.z;
    const int seg = blockIdx.y;
    const int tid = threadIdx.x;
    const int wid = tid >> 6;
    const int lane = tid & 63;
    const int l15 = lane & 15;
    const int lg  = lane >> 4;
    const int qw  = blockIdx.x * 128 + wid * 32;

    const f16* thb = th + (size_t)b * NN * CI;
    const f16* phb = ph + (size_t)b * NN * CI;
    const f16* gTb = gT + (size_t)b * (NN/32) * (CI*32);

    // persistent theta B-frags: 2 q-tiles x 4 k-frags
    f16x8 bf[2][4];
    #pragma unroll
    for (int qt = 0; qt < 2; ++qt) {
        const f16* trow = thb + (size_t)(qw + qt*16 + l15) * CI + lg * 8;
        #pragma unroll
        for (int kk = 0; kk < 4; ++kk)
            bf[qt][kk] = *reinterpret_cast<const f16x8*>(trow + kk * 32);
    }

    f32x4 acc[2][8];              // Y^T: per q-tile, 8 ci-tiles, col=q
    f32x4 accl[2];                // row-sums (ones trick)
    float m[2] = {-INFINITY, -INFINITY};
    #pragma unroll
    for (int qt = 0; qt < 2; ++qt) {
        #pragma unroll
        for (int ct = 0; ct < 8; ++ct) acc[qt][ct] = (f32x4){0.f,0.f,0.f,0.f};
        accl[qt] = (f32x4){0.f,0.f,0.f,0.f};
    }

    const f16x8 onesA = {(f16)1,(f16)1,(f16)1,(f16)1,(f16)1,(f16)1,(f16)1,(f16)1};

    // phi staging: 32 rows x 128 c, XOR-swizzled
    const int prow = tid >> 3, pcol = (tid & 7) * 16;
    const int pswz = (prow & 7) << 3;
    const int pc0 = pcol ^ pswz, pc1 = (pcol + 8) ^ pswz;
    // g staging: tiled source (contiguous 8KB), dest [ci][kv] XOR-swizzled
    const int grow = tid >> 1, gcs = (tid & 1) * 16;
    const int gswz = ((grow >> 1) & 3) << 3;
    const int gc0 = gcs ^ gswz, gc1 = (gcs + 8) ^ gswz;

    const int kv_base = seg * KVSEG;
    const int t0 = kv_base >> 5;
    const int xsw = (l15 & 7) << 3;

    #pragma unroll 1
    for (int it = 0; it < NIT; ++it) {
        const int kv0 = kv_base + it * 32;

        // ---- issue loads at top (coalesced; g source fully contiguous) ----
        const f16* ps = phb + (size_t)(kv0 + prow) * CI + pcol;
        f16x8 pv0 = *reinterpret_cast<const f16x8*>(ps);
        f16x8 pv1 = *reinterpret_cast<const f16x8*>(ps + 8);
        const f16* gs = gTb + (size_t)(t0 + it) * (CI*32) + tid * 16;
        f16x8 gv0 = *reinterpret_cast<const f16x8*>(gs);
        f16x8 gv1 = *reinterpret_cast<const f16x8*>(gs + 8);

        __syncthreads();
        *reinterpret_cast<f16x8*>(&ph_lds[prow*128 + pc0]) = pv0;
        *reinterpret_cast<f16x8*>(&ph_lds[prow*128 + pc1]) = pv1;
        *reinterpret_cast<f16x8*>(&g_lds[grow*32 + gc0])   = gv0;
        *reinterpret_cast<f16x8*>(&g_lds[grow*32 + gc1])   = gv1;
        __syncthreads();

        // ---- S^T = phi @ theta^T : 2 kv-tiles x 2 q-tiles ----
        f32x4 s00 = (f32x4){0.f,0.f,0.f,0.f}, s01 = (f32x4){0.f,0.f,0.f,0.f};
        f32x4 s10 = (f32x4){0.f,0.f,0.f,0.f}, s11 = (f32x4){0.f,0.f,0.f,0.f};
        #pragma unroll
        for (int kk = 0; kk < 4; ++kk) {
            const int coff = (kk*32 + lg*8) ^ xsw;
            f16x8 a0 = *reinterpret_cast<const f16x8*>(&ph_lds[l15*128 + coff]);
            f16x8 a1 = *reinterpret_cast<const f16x8*>(&ph_lds[(16 + l15)*128 + coff]);
            s00 = __builtin_amdgcn_mfma_f32_16x16x32_f16(a0, bf[0][kk], s00, 0, 0, 0);
            s01 = __builtin_amdgcn_mfma_f32_16x16x32_f16(a1, bf[0][kk], s01, 0, 0, 0);
            s10 = __builtin_amdgcn_mfma_f32_16x16x32_f16(a0, bf[1][kk], s10, 0, 0, 0);
            s11 = __builtin_amdgcn_mfma_f32_16x16x32_f16(a1, bf[1][kk], s11, 0, 0, 0);
        }

        // ---- online max per q-tile (lane-local column), defer-rescale ----
        float tm0 = fmaxf(fmaxf(fmaxf(s00[0], s00[1]), fmaxf(s00[2], s00[3])),
                          fmaxf(fmaxf(s01[0], s01[1]), fmaxf(s01[2], s01[3])));
        float tm1 = fmaxf(fmaxf(fmaxf(s10[0], s10[1]), fmaxf(s10[2], s10[3])),
                          fmaxf(fmaxf(s11[0], s11[1]), fmaxf(s11[2], s11[3])));
        tm0 = fmaxf(tm0, __shfl_xor(tm0, 16));
        tm0 = fmaxf(tm0, __shfl_xor(tm0, 32));
        tm1 = fmaxf(tm1, __shfl_xor(tm1, 16));
        tm1 = fmaxf(tm1, __shfl_xor(tm1, 32));
        if (__any((tm0 > m[0] + THR) || (tm1 > m[1] + THR))) {
            float nm0 = fmaxf(m[0], tm0), nm1 = fmaxf(m[1], tm1);
            float sc0 = __builtin_amdgcn_exp2f(m[0] - nm0);
            float sc1 = __builtin_amdgcn_exp2f(m[1] - nm1);
            m[0] = nm0; m[1] = nm1;
            #pragma unroll
            for (int ct = 0; ct < 8; ++ct) {
                acc[0][ct][0] *= sc0; acc[0][ct][1] *= sc0; acc[0][ct][2] *= sc0; acc[0][ct][3] *= sc0;
                acc[1][ct][0] *= sc1; acc[1][ct][1] *= sc1; acc[1][ct][2] *= sc1; acc[1][ct][3] *= sc1;
            }
            accl[0][0] *= sc0; accl[0][1] *= sc0; accl[0][2] *= sc0; accl[0][3] *= sc0;
            accl[1][0] *= sc1; accl[1][1] *= sc1; accl[1][2] *= sc1; accl[1][3] *= sc1;
        }

        // ---- P^T = exp2(S^T - m), pack f16, exchange via per-wave LDS ----
        {
            union { fp16v2 h[2]; float2 f; } u0, u1;
            u0.h[0] = __builtin_amdgcn_cvt_pkrtz(__builtin_amdgcn_exp2f(s00[0] - m[0]),
                                                 __builtin_amdgcn_exp2f(s00[1] - m[0]));
            u0.h[1] = __builtin_amdgcn_cvt_pkrtz(__builtin_amdgcn_exp2f(s00[2] - m[0]),
                                                 __builtin_amdgcn_exp2f(s00[3] - m[0]));
            u1.h[0] = __builtin_amdgcn_cvt_pkrtz(__builtin_amdgcn_exp2f(s01[0] - m[0]),
                                                 __builtin_amdgcn_exp2f(s01[1] - m[0]));
            u1.h[1] = __builtin_amdgcn_cvt_pkrtz(__builtin_amdgcn_exp2f(s01[2] - m[0]),
                                                 __builtin_amdgcn_exp2f(s01[3] - m[0]));
            *reinterpret_cast<float2*>(&pT_lds[wid][0][l15][4*lg])      = u0.f;
            *reinterpret_cast<float2*>(&pT_lds[wid][0][l15][16 + 4*lg]) = u1.f;
            u0.h[0] = __builtin_amdgcn_cvt_pkrtz(__builtin_amdgcn_exp2f(s10[0] - m[1]),
                                                 __builtin_amdgcn_exp2f(s10[1] - m[1]));
            u0.h[1] = __builtin_amdgcn_cvt_pkrtz(__builtin_amdgcn_exp2f(s10[2] - m[1]),
                                                 __builtin_amdgcn_exp2f(s10[3] - m[1]));
            u1.h[0] = __builtin_amdgcn_cvt_pkrtz(__builtin_amdgcn_exp2f(s11[0] - m[1]),
                                                 __builtin_amdgcn_exp2f(s11[1] - m[1]));
            u1.h[1] = __builtin_amdgcn_cvt_pkrtz(__builtin_amdgcn_exp2f(s11[2] - m[1]),
                                                 __builtin_amdgcn_exp2f(s11[3] - m[1]));
            *reinterpret_cast<float2*>(&pT_lds[wid][1][l15][4*lg])      = u0.f;
            *reinterpret_cast<float2*>(&pT_lds[wid][1][l15][16 + 4*lg]) = u1.f;
        }
        asm volatile("s_waitcnt lgkmcnt(0)" ::: "memory");
        f16x8 pa0 = *reinterpret_cast<const f16x8*>(&pT_lds[wid][0][l15][8*lg]);
        f16x8 pa1 = *reinterpret_cast<const f16x8*>(&pT_lds[wid][1][l15][8*lg]);

        // ---- Y^T += gT @ P^T (swizzled g reads, conflict-free) ----
        const int grsw = ((l15 >> 1) & 3) << 3;
        #pragma unroll
        for (int ct = 0; ct < 8; ++ct) {
            f16x8 ga = *reinterpret_cast<const f16x8*>(&g_lds[(ct*16 + l15)*32 + (lg*8 ^ grsw)]);
            acc[0][ct] = __builtin_amdgcn_mfma_f32_16x16x32_f16(ga, pa0, acc[0][ct], 0, 0, 0);
            acc[1][ct] = __builtin_amdgcn_mfma_f32_16x16x32_f16(ga, pa1, acc[1][ct], 0, 0, 0);
        }
        accl[0] = __builtin_amdgcn_mfma_f32_16x16x32_f16(onesA, pa0, accl[0], 0, 0, 0);
        accl[1] = __builtin_amdgcn_mfma_f32_16x16x32_f16(onesA, pa1, accl[1], 0, 0, 0);
    }

    // ---- store NORMALIZED partials (acc/l) as f16: pacc[bs][ci][n] ----
    const float inv[2] = {1.0f / accl[0][0], 1.0f / accl[1][0]};
    #pragma unroll
    for (int qt = 0; qt < 2; ++qt) {
        f16* pb = pacc + (size_t)(b*SEG + seg) * CI * NN + qw + qt*16 + l15;
        #pragma unroll
        for (int ct = 0; ct < 8; ++ct)
            #pragma unroll
            for (int r = 0; r < 4; ++r)
                pb[(size_t)(ct*16 + lg*4 + r) * NN] = (f16)(acc[qt][ct][r] * inv[qt]);
    }

    if (lg == 0) {
        #pragma unroll
        for (int qt = 0; qt < 2; ++qt) {
            float* mlb = pml + ((size_t)(b*SEG + seg) * NN + qw + qt*16 + l15) * 2;
            mlb[0] = m[qt];
            mlb[1] = accl[qt][0];
        }
    }
}

// ---------------- kernel 3: merge normalized partials -> yh (f16 [pos][ci]) ---------
// y_q = sum_s w_s*l_s*accn_s / sum_s w_s*l_s,  w_s = exp2(m_s - M)
__global__ __launch_bounds__(256) void combine_kernel(
    const f16* __restrict__ pacc, const float* __restrict__ pml,
    f16* __restrict__ yh)
{
    const int qL = threadIdx.x & 31;
    const int cg = threadIdx.x >> 5;          // 0..7, 16 ci each
    const int q  = blockIdx.x * 32 + qL;
    const int b  = blockIdx.y;

    float mv[SEG], lv[SEG];
    #pragma unroll
    for (int s = 0; s < SEG; ++s) {
        const float* p = pml + ((size_t)(b*SEG + s) * NN + q) * 2;
        mv[s] = p[0];
        lv[s] = p[1];
    }
    float M = mv[0];
    #pragma unroll
    for (int s = 1; s < SEG; ++s) M = fmaxf(M, mv[s]);
    float wsum = 0.f, wl[SEG];
    #pragma unroll
    for (int s = 0; s < SEG; ++s) {
        wl[s] = __builtin_amdgcn_exp2f(mv[s] - M) * lv[s];
        wsum += wl[s];
    }
    const float inv = 1.0f / wsum;

    const int c0 = cg * 16;
    float o[16];
    #pragma unroll
    for (int i = 0; i < 16; ++i) o[i] = 0.f;
    for (int s = 0; s < SEG; ++s) {
        const f16* pb = pacc + ((size_t)(b*SEG + s) * CI + c0) * NN + q;
        #pragma unroll
        for (int i = 0; i < 16; ++i)
            o[i] = fmaf(wl[s], (float)pb[(size_t)i * NN], o[i]);
    }
    f16 oh[16];
    #pragma unroll
    for (int i = 0; i < 16; ++i) oh[i] = (f16)(o[i] * inv);
    f16* yo = yh + ((size_t)b * NN + q) * CI + c0;
    *reinterpret_cast<f16x8*>(yo)     = *reinterpret_cast<f16x8*>(&oh[0]);
    *reinterpret_cast<f16x8*>(yo + 8) = *reinterpret_cast<f16x8*>(&oh[8]);
}

// ---------------- kernel 4: out GEMM (MFMA) + BN + residual ----------------
__global__ __launch_bounds__(256) void out_gemm(
    const float* __restrict__ x, const f16* __restrict__ yh, const f16* __restrict__ WoT,
    const float* __restrict__ bnsc, const float* __restrict__ bnsh, float* __restrict__ out)
{
    const int tid = threadIdx.x;
    const int wid = tid >> 6, lane = tid & 63;
    const int l15 = lane & 15, lg = lane >> 4;
    const int p0 = blockIdx.x * 16;
    const int nq = wid;

    f32x4 acc[4];
    #pragma unroll
    for (int t = 0; t < 4; ++t) acc[t] = (f32x4){0.f,0.f,0.f,0.f};

    const f16* ya = yh + (size_t)(p0 + l15)*CI + lg*8;
    const f16* wb = WoT + (size_t)(nq*64 + l15)*CI + lg*8;
    #pragma unroll
    for (int kk = 0; kk < 4; ++kk) {
        f16x8 a = *reinterpret_cast<const f16x8*>(ya + kk*32);
        #pragma unroll
        for (int t = 0; t < 4; ++t) {
            f16x8 bfr = *reinterpret_cast<const f16x8*>(wb + (size_t)t*16*CI + kk*32);
            acc[t] = __builtin_amdgcn_mfma_f32_16x16x32_f16(a, bfr, acc[t], 0, 0, 0);
        }
    }

    #pragma unroll
    for (int t = 0; t < 4; ++t) {
        const int ci = nq*64 + t*16 + l15;
        const float sc = bnsc[ci], sh = bnsh[ci];
        #pragma unroll
        for (int r = 0; r < 4; ++r) {
            const size_t idx = (size_t)(p0 + lg*4 + r)*CC + ci;
            out[idx] = x[idx] + fmaf(sc, acc[t][r], sh);
        }
    }
}

extern "C" void kernel_launch(void* const* d_in, const int* in_sizes, int n_in,
                              void* d_out, int out_size, void* d_ws, size_t ws_size,
                              hipStream_t stream)
{
    const float* x     = (const float*)d_in[0];
    const float* Wg    = (const float*)d_in[1];
    const float* bg    = (const float*)d_in[2];
    const float* Wt    = (const float*)d_in[3];
    const float* bt    = (const float*)d_in[4];
    const float* Wp    = (const float*)d_in[5];
    const float* bp    = (const float*)d_in[6];
    const float* Wo    = (const float*)d_in[7];
    const float* bo    = (const float*)d_in[8];
    const float* gamma = (const float*)d_in[9];
    const float* beta  = (const float*)d_in[10];
    const float* mmean = (const float*)d_in[11];
    const float* mvar  = (const float*)d_in[12];
    float* out = (float*)d_out;

    const size_t PB = (size_t)BB * NN * CI;                 // 1,605,632
    f16*   th   = (f16*)d_ws;                               // 3.2 MB
    f16*   ph   = th + PB;                                  // 3.2 MB
    f16*   gT   = ph + PB;                                  // 3.2 MB (tiled layout)
    f16*   pacc = gT + PB;                                  // BB*SEG*NN*CI f16 = 45 MB
    float* pml  = (float*)(pacc + (size_t)BB * SEG * NN * CI);  // 1.4 MB
    f16*   yh   = (f16*)(pml + (size_t)BB * SEG * NN * 2);  // 3.2 MB
    f16*   WallT= yh + PB;                                  // 197 KB
    f16*   WoT  = WallT + 384*256;                          // 66 KB
    float* ball = (float*)(WoT + 256*CI);                   // 1.5 KB
    float* bnsc = ball + 384;
    float* bnsh = bnsc + 256;

    prep_kernel<<<516, 256, 0, stream>>>(Wg, Wt, Wp, Wo, bg, bt, bp, bo,
                                         gamma, beta, mmean, mvar,
                                         WallT, WoT, ball, bnsc, bnsh);
    proj_gemm<<<BB * NN / 16, 256, 0, stream>>>(x, WallT, ball, th, ph, gT);
    attn_kernel<<<dim3(NN / 128, SEG, BB), 256, 0, stream>>>(th, ph, gT, pacc, pml);
    combine_kernel<<<dim3(NN / 32, BB), 256, 0, stream>>>(pacc, pml, yh);
    out_gemm<<<BB * NN / 16, 256, 0, stream>>>(x, yh, WoT, bnsc, bnsh, out);
}

// Round 12
// 96.621 us; speedup vs baseline: 1.6116x; 1.2707x over previous
//
#include <hip/hip_runtime.h>

#define BB 2
#define NN 6272
#define CC 256
#define CI 128
#define SEG 7
#define KVSEG (NN / SEG)          // 896 kv per segment, 28 tiles of 32
#define NIT (KVSEG / 32)
#define LOG2E 1.44269504088896f
#define THR 12.0f                 // defer-max threshold (log2 domain), P <= 4096 fits f16

typedef _Float16 f16;
typedef __attribute__((ext_vector_type(2))) __fp16 fp16v2;   // cvt_pkrtz native type
typedef __attribute__((ext_vector_type(8))) _Float16 f16x8;
typedef __attribute__((ext_vector_type(4))) float f32x4;

// ---------------- kernel 0: weight prep (once, ~3us) ----------------
__global__ __launch_bounds__(256) void prep_kernel(
    const float* __restrict__ Wg, const float* __restrict__ Wt, const float* __restrict__ Wp,
    const float* __restrict__ Wo, const float* __restrict__ bg, const float* __restrict__ bt,
    const float* __restrict__ bp, const float* __restrict__ bo,
    const float* __restrict__ gamma, const float* __restrict__ beta,
    const float* __restrict__ mmean, const float* __restrict__ mvar,
    f16* __restrict__ WallT, f16* __restrict__ WoT,
    float* __restrict__ ball, float* __restrict__ bnsc, float* __restrict__ bnsh)
{
    const int idx = blockIdx.x * 256 + threadIdx.x;
    if (idx < 384*256) {
        const int j = idx >> 8, k = idx & 255;
        float v;
        if (j < 128)      v = Wg[k*CI + j];
        else if (j < 256) v = Wt[k*CI + (j-128)] * LOG2E;
        else              v = Wp[k*CI + (j-256)];
        WallT[j*256 + k] = (f16)v;
    } else if (idx < 384*256 + 256*128) {
        const int i2 = idx - 384*256;
        const int ci = i2 >> 7, k = i2 & 127;
        WoT[ci*CI + k] = (f16)Wo[k*CC + ci];
    } else {
        const int i3 = idx - (384*256 + 256*128);
        if (i3 < 384) {
            float v;
            if (i3 < 128)      v = bg[i3];
            else if (i3 < 256) v = bt[i3-128] * LOG2E;
            else               v = bp[i3-256];
            ball[i3] = v;
        } else if (i3 < 640) {
            const int c = i3 - 384;
            bnsc[c] = gamma[c] * rsqrtf(mvar[c] + 1e-3f);
        } else if (i3 < 896) {
            const int c = i3 - 640;
            float sc = gamma[c] * rsqrtf(mvar[c] + 1e-3f);
            bnsh[c] = beta[c] + sc * (bo[c] - mmean[c]);
        }
    }
}

// ---------------- kernel 1: fused projection GEMM (MFMA), 32-pos tile ----------------
// [32 pos] x [256 k] x [384 j] per block; 4 waves; wave owns 96 j x 32 pos
// (2 pos-tiles x 6 j-tiles; each B-frag feeds 2 MFMAs). Block covers exactly one
// gT tile: gT tiled [b][n/32][ci][32], stored as one contiguous 8KB write.
__global__ __launch_bounds__(256) void proj_gemm(
    const float* __restrict__ x, const f16* __restrict__ WallT, const float* __restrict__ ball,
    f16* __restrict__ th, f16* __restrict__ ph, f16* __restrict__ gT)
{
    __shared__ __align__(16) f16 xls[32*264];   // 16.9KB
    __shared__ __align__(16) f16 gls[128*40];   // 10.2KB (pad 40: rows 16B-aligned)

    const int tid = threadIdx.x;
    const int wid = tid >> 6, lane = tid & 63;
    const int l15 = lane & 15, lg = lane >> 4;
    const int p0 = blockIdx.x * 32;

    {   // stage x tile 32x256 -> f16 LDS (64B per thread)
        const int row = tid >> 3, c0 = (tid & 7) * 32;
        const float* xsrc = x + (size_t)(p0 + row) * CC + c0;
        f16 buf[32];
        #pragma unroll
        for (int i = 0; i < 8; ++i) {
            float4 v = *reinterpret_cast<const float4*>(xsrc + 4*i);
            buf[4*i+0]=(f16)v.x; buf[4*i+1]=(f16)v.y; buf[4*i+2]=(f16)v.z; buf[4*i+3]=(f16)v.w;
        }
        #pragma unroll
        for (int i = 0; i < 4; ++i)
            *reinterpret_cast<f16x8*>(&xls[row*264 + c0 + 8*i]) =
                *reinterpret_cast<f16x8*>(&buf[8*i]);
    }
    __syncthreads();

    f32x4 acc[2][6];
    #pragma unroll
    for (int pt = 0; pt < 2; ++pt)
        #pragma unroll
        for (int t = 0; t < 6; ++t) acc[pt][t] = (f32x4){0.f,0.f,0.f,0.f};

    const f16* wbase = WallT + (size_t)(wid*96 + l15)*256 + lg*8;
    for (int kk = 0; kk < 8; ++kk) {
        f16x8 a0 = *reinterpret_cast<const f16x8*>(&xls[l15*264 + kk*32 + lg*8]);
        f16x8 a1 = *reinterpret_cast<const f16x8*>(&xls[(16 + l15)*264 + kk*32 + lg*8]);
        #pragma unroll
        for (int t = 0; t < 6; ++t) {
            f16x8 bfr = *reinterpret_cast<const f16x8*>(wbase + (size_t)t*16*256 + kk*32);
            acc[0][t] = __builtin_amdgcn_mfma_f32_16x16x32_f16(a0, bfr, acc[0][t], 0, 0, 0);
            acc[1][t] = __builtin_amdgcn_mfma_f32_16x16x32_f16(a1, bfr, acc[1][t], 0, 0, 0);
        }
    }

    const int bidx = (p0 >= NN) ? 1 : 0;
    const int n0 = p0 - bidx * NN;

    #pragma unroll
    for (int t = 0; t < 6; ++t) {
        const int j0 = wid*96 + t*16;          // + l15 per lane
        const float bv = ball[j0 + l15];
        if (j0 < 128) {          // g -> LDS transpose [ci][pos]
            #pragma unroll
            for (int pt = 0; pt < 2; ++pt)
                #pragma unroll
                for (int r = 0; r < 4; ++r)
                    gls[(j0 + l15)*40 + pt*16 + lg*4 + r] = (f16)(acc[pt][t][r] + bv);
        } else if (j0 < 256) {   // theta (pre-scaled)
            #pragma unroll
            for (int pt = 0; pt < 2; ++pt) {
                f16* dst = th + (size_t)(p0 + pt*16 + lg*4)*CI + (j0 - 128) + l15;
                #pragma unroll
                for (int r = 0; r < 4; ++r)
                    dst[(size_t)r*CI] = (f16)(acc[pt][t][r] + bv);
            }
        } else {                 // phi
            #pragma unroll
            for (int pt = 0; pt < 2; ++pt) {
                f16* dst = ph + (size_t)(p0 + pt*16 + lg*4)*CI + (j0 - 256) + l15;
                #pragma unroll
                for (int r = 0; r < 4; ++r)
                    dst[(size_t)r*CI] = (f16)(acc[pt][t][r] + bv);
            }
        }
    }
    __syncthreads();
    {   // one full contiguous gT tile store (8KB)
        const int ci = tid >> 1, half = tid & 1;
        f16x8 v0 = *reinterpret_cast<const f16x8*>(&gls[ci*40 + half*16]);
        f16x8 v1 = *reinterpret_cast<const f16x8*>(&gls[ci*40 + half*16 + 8]);
        f16* gdst = gT + ((size_t)bidx*(NN/32) + (n0 >> 5))*(CI*32) + ci*32 + half*16;
        *reinterpret_cast<f16x8*>(gdst)     = v0;
        *reinterpret_cast<f16x8*>(gdst + 8) = v1;
    }
}

// ---------------- kernel 2: split-KV flash attention (R11 body, SEG=7) --------------
__global__ __launch_bounds__(256, 3) void attn_kernel(
    const f16* __restrict__ th, const f16* __restrict__ ph,
    const f16* __restrict__ gT, f16* __restrict__ pacc, float* __restrict__ pml)
{
    __shared__ __align__(16) f16 ph_lds[32 * 128];     // [kv][c], swizzled
    __shared__ __align__(16) f16 g_lds[128 * 32];      // [ci][kv], swizzled
    __shared__ __align__(16) f16 pT_lds[4][2][16][40]; // per-wave [qt][q][kv+pad]

    const int b   = blockIdx.z;
    const int seg = blockIdx.y;
    const int tid = threadIdx.x;
    const int wid = tid >> 6;
    const int lane = tid & 63;
    const int l15 = lane & 15;
    const int lg  = lane >> 4;
    const int qw  = blockIdx.x * 128 + wid * 32;

    const f16* thb = th + (size_t)b * NN * CI;
    const f16* phb = ph + (size_t)b * NN * CI;
    const f16* gTb = gT + (size_t)b * (NN/32) * (CI*32);

    // persistent theta B-frags: 2 q-tiles x 4 k-frags
    f16x8 bf[2][4];
    #pragma unroll
    for (int qt = 0; qt < 2; ++qt) {
        const f16* trow = thb + (size_t)(qw + qt*16 + l15) * CI + lg * 8;
        #pragma unroll
        for (int kk = 0; kk < 4; ++kk)
            bf[qt][kk] = *reinterpret_cast<const f16x8*>(trow + kk * 32);
    }

    f32x4 acc[2][8];              // Y^T: per q-tile, 8 ci-tiles, col=q
    f32x4 accl[2];                // row-sums (ones trick)
    float m[2] = {-INFINITY, -INFINITY};
    #pragma unroll
    for (int qt = 0; qt < 2; ++qt) {
        #pragma unroll
        for (int ct = 0; ct < 8; ++ct) acc[qt][ct] = (f32x4){0.f,0.f,0.f,0.f};
        accl[qt] = (f32x4){0.f,0.f,0.f,0.f};
    }

    const f16x8 onesA = {(f16)1,(f16)1,(f16)1,(f16)1,(f16)1,(f16)1,(f16)1,(f16)1};

    // phi staging: 32 rows x 128 c, XOR-swizzled
    const int prow = tid >> 3, pcol = (tid & 7) * 16;
    const int pswz = (prow & 7) << 3;
    const int pc0 = pcol ^ pswz, pc1 = (pcol + 8) ^ pswz;
    // g staging: tiled source (contiguous 8KB), dest [ci][kv] XOR-swizzled
    const int grow = tid >> 1, gcs = (tid & 1) * 16;
    const int gswz = ((grow >> 1) & 3) << 3;
    const int gc0 = gcs ^ gswz, gc1 = (gcs + 8) ^ gswz;

    const int kv_base = seg * KVSEG;
    const int t0 = kv_base >> 5;
    const int xsw = (l15 & 7) << 3;

    #pragma unroll 1
    for (int it = 0; it < NIT; ++it) {
        const int kv0 = kv_base + it * 32;

        // ---- issue loads at top (coalesced; g source fully contiguous) ----
        const f16* ps = phb + (size_t)(kv0 + prow) * CI + pcol;
        f16x8 pv0 = *reinterpret_cast<const f16x8*>(ps);
        f16x8 pv1 = *reinterpret_cast<const f16x8*>(ps + 8);
        const f16* gs = gTb + (size_t)(t0 + it) * (CI*32) + tid * 16;
        f16x8 gv0 = *reinterpret_cast<const f16x8*>(gs);
        f16x8 gv1 = *reinterpret_cast<const f16x8*>(gs + 8);

        __syncthreads();
        *reinterpret_cast<f16x8*>(&ph_lds[prow*128 + pc0]) = pv0;
        *reinterpret_cast<f16x8*>(&ph_lds[prow*128 + pc1]) = pv1;
        *reinterpret_cast<f16x8*>(&g_lds[grow*32 + gc0])   = gv0;
        *reinterpret_cast<f16x8*>(&g_lds[grow*32 + gc1])   = gv1;
        __syncthreads();

        // ---- S^T = phi @ theta^T : 2 kv-tiles x 2 q-tiles ----
        f32x4 s00 = (f32x4){0.f,0.f,0.f,0.f}, s01 = (f32x4){0.f,0.f,0.f,0.f};
        f32x4 s10 = (f32x4){0.f,0.f,0.f,0.f}, s11 = (f32x4){0.f,0.f,0.f,0.f};
        #pragma unroll
        for (int kk = 0; kk < 4; ++kk) {
            const int coff = (kk*32 + lg*8) ^ xsw;
            f16x8 a0 = *reinterpret_cast<const f16x8*>(&ph_lds[l15*128 + coff]);
            f16x8 a1 = *reinterpret_cast<const f16x8*>(&ph_lds[(16 + l15)*128 + coff]);
            s00 = __builtin_amdgcn_mfma_f32_16x16x32_f16(a0, bf[0][kk], s00, 0, 0, 0);
            s01 = __builtin_amdgcn_mfma_f32_16x16x32_f16(a1, bf[0][kk], s01, 0, 0, 0);
            s10 = __builtin_amdgcn_mfma_f32_16x16x32_f16(a0, bf[1][kk], s10, 0, 0, 0);
            s11 = __builtin_amdgcn_mfma_f32_16x16x32_f16(a1, bf[1][kk], s11, 0, 0, 0);
        }

        // ---- online max per q-tile (lane-local column), defer-rescale ----
        float tm0 = fmaxf(fmaxf(fmaxf(s00[0], s00[1]), fmaxf(s00[2], s00[3])),
                          fmaxf(fmaxf(s01[0], s01[1]), fmaxf(s01[2], s01[3])));
        float tm1 = fmaxf(fmaxf(fmaxf(s10[0], s10[1]), fmaxf(s10[2], s10[3])),
                          fmaxf(fmaxf(s11[0], s11[1]), fmaxf(s11[2], s11[3])));
        tm0 = fmaxf(tm0, __shfl_xor(tm0, 16));
        tm0 = fmaxf(tm0, __shfl_xor(tm0, 32));
        tm1 = fmaxf(tm1, __shfl_xor(tm1, 16));
        tm1 = fmaxf(tm1, __shfl_xor(tm1, 32));
        if (__any((tm0 > m[0] + THR) || (tm1 > m[1] + THR))) {
            float nm0 = fmaxf(m[0], tm0), nm1 = fmaxf(m[1], tm1);
            float sc0 = __builtin_amdgcn_exp2f(m[0] - nm0);
            float sc1 = __builtin_amdgcn_exp2f(m[1] - nm1);
            m[0] = nm0; m[1] = nm1;
            #pragma unroll
            for (int ct = 0; ct < 8; ++ct) {
                acc[0][ct][0] *= sc0; acc[0][ct][1] *= sc0; acc[0][ct][2] *= sc0; acc[0][ct][3] *= sc0;
                acc[1][ct][0] *= sc1; acc[1][ct][1] *= sc1; acc[1][ct][2] *= sc1; acc[1][ct][3] *= sc1;
            }
            accl[0][0] *= sc0; accl[0][1] *= sc0; accl[0][2] *= sc0; accl[0][3] *= sc0;
            accl[1][0] *= sc1; accl[1][1] *= sc1; accl[1][2] *= sc1; accl[1][3] *= sc1;
        }

        // ---- P^T = exp2(S^T - m), pack f16, exchange via per-wave LDS ----
        {
            union { fp16v2 h[2]; float2 f; } u0, u1;
            u0.h[0] = __builtin_amdgcn_cvt_pkrtz(__builtin_amdgcn_exp2f(s00[0] - m[0]),
                                                 __builtin_amdgcn_exp2f(s00[1] - m[0]));
            u0.h[1] = __builtin_amdgcn_cvt_pkrtz(__builtin_amdgcn_exp2f(s00[2] - m[0]),
                                                 __builtin_amdgcn_exp2f(s00[3] - m[0]));
            u1.h[0] = __builtin_amdgcn_cvt_pkrtz(__builtin_amdgcn_exp2f(s01[0] - m[0]),
                                                 __builtin_amdgcn_exp2f(s01[1] - m[0]));
            u1.h[1] = __builtin_amdgcn_cvt_pkrtz(__builtin_amdgcn_exp2f(s01[2] - m[0]),
                                                 __builtin_amdgcn_exp2f(s01[3] - m[0]));
            *reinterpret_cast<float2*>(&pT_lds[wid][0][l15][4*lg])      = u0.f;
            *reinterpret_cast<float2*>(&pT_lds[wid][0][l15][16 + 4*lg]) = u1.f;
            u0.h[0] = __builtin_amdgcn_cvt_pkrtz(__builtin_amdgcn_exp2f(s10[0] - m[1]),
                                                 __builtin_amdgcn_exp2f(s10[1] - m[1]));
            u0.h[1] = __builtin_amdgcn_cvt_pkrtz(__builtin_amdgcn_exp2f(s10[2] - m[1]),
                                                 __builtin_amdgcn_exp2f(s10[3] - m[1]));
            u1.h[0] = __builtin_amdgcn_cvt_pkrtz(__builtin_amdgcn_exp2f(s11[0] - m[1]),
                                                 __builtin_amdgcn_exp2f(s11[1] - m[1]));
            u1.h[1] = __builtin_amdgcn_cvt_pkrtz(__builtin_amdgcn_exp2f(s11[2] - m[1]),
                                                 __builtin_amdgcn_exp2f(s11[3] - m[1]));
            *reinterpret_cast<float2*>(&pT_lds[wid][1][l15][4*lg])      = u0.f;
            *reinterpret_cast<float2*>(&pT_lds[wid][1][l15][16 + 4*lg]) = u1.f;
        }
        asm volatile("s_waitcnt lgkmcnt(0)" ::: "memory");
        f16x8 pa0 = *reinterpret_cast<const f16x8*>(&pT_lds[wid][0][l15][8*lg]);
        f16x8 pa1 = *reinterpret_cast<const f16x8*>(&pT_lds[wid][1][l15][8*lg]);

        // ---- Y^T += gT @ P^T (swizzled g reads, conflict-free) ----
        const int grsw = ((l15 >> 1) & 3) << 3;
        #pragma unroll
        for (int ct = 0; ct < 8; ++ct) {
            f16x8 ga = *reinterpret_cast<const f16x8*>(&g_lds[(ct*16 + l15)*32 + (lg*8 ^ grsw)]);
            acc[0][ct] = __builtin_amdgcn_mfma_f32_16x16x32_f16(ga, pa0, acc[0][ct], 0, 0, 0);
            acc[1][ct] = __builtin_amdgcn_mfma_f32_16x16x32_f16(ga, pa1, acc[1][ct], 0, 0, 0);
        }
        accl[0] = __builtin_amdgcn_mfma_f32_16x16x32_f16(onesA, pa0, accl[0], 0, 0, 0);
        accl[1] = __builtin_amdgcn_mfma_f32_16x16x32_f16(onesA, pa1, accl[1], 0, 0, 0);
    }

    // ---- store NORMALIZED partials (acc/l) as f16: pacc[bs][ci][n] ----
    const float inv[2] = {1.0f / accl[0][0], 1.0f / accl[1][0]};
    #pragma unroll
    for (int qt = 0; qt < 2; ++qt) {
        f16* pb = pacc + (size_t)(b*SEG + seg) * CI * NN + qw + qt*16 + l15;
        #pragma unroll
        for (int ct = 0; ct < 8; ++ct)
            #pragma unroll
            for (int r = 0; r < 4; ++r)
                pb[(size_t)(ct*16 + lg*4 + r) * NN] = (f16)(acc[qt][ct][r] * inv[qt]);
    }

    if (lg == 0) {
        #pragma unroll
        for (int qt = 0; qt < 2; ++qt) {
            float* mlb = pml + ((size_t)(b*SEG + seg) * NN + qw + qt*16 + l15) * 2;
            mlb[0] = m[qt];
            mlb[1] = accl[qt][0];
        }
    }
}

// ---------------- kernel 3: fused combine + out GEMM + BN + residual ----------------
// [32 pos] per block. Phase 0: 32 threads compute normalized segment weights.
// Phase 1: weighted sum of f16 normalized partials -> yls (transposed to [pos][ci]).
// Phase 2: MFMA GEMM yls @ WoT + BN + residual.
__global__ __launch_bounds__(256) void out_gemm(
    const float* __restrict__ x, const f16* __restrict__ pacc, const float* __restrict__ pml,
    const f16* __restrict__ WoT, const float* __restrict__ bnsc, const float* __restrict__ bnsh,
    float* __restrict__ out)
{
    __shared__ __align__(16) f16 yls[32*136];   // [pos][ci], pad 136 (rows 16B-aligned)
    __shared__ float wl_lds[SEG][32];           // normalized weight per (seg, pos)

    const int tid = threadIdx.x;
    const int p0 = blockIdx.x * 32;
    const int bidx = (p0 >= NN) ? 1 : 0;
    const int n0 = p0 - bidx * NN;

    // ---- phase 0: per-position segment weights (32 threads) ----
    if (tid < 32) {
        const int q = n0 + tid;
        float mv[SEG], lv[SEG];
        #pragma unroll
        for (int s = 0; s < SEG; ++s) {
            const float* p = pml + ((size_t)(bidx*SEG + s) * NN + q) * 2;
            mv[s] = p[0];
            lv[s] = p[1];
        }
        float M = mv[0];
        #pragma unroll
        for (int s = 1; s < SEG; ++s) M = fmaxf(M, mv[s]);
        float wl[SEG], wsum = 0.f;
        #pragma unroll
        for (int s = 0; s < SEG; ++s) {
            wl[s] = __builtin_amdgcn_exp2f(mv[s] - M) * lv[s];
            wsum += wl[s];
        }
        const float inv = 1.0f / wsum;
        #pragma unroll
        for (int s = 0; s < SEG; ++s) wl_lds[s][tid] = wl[s] * inv;
    }
    __syncthreads();

    // ---- phase 1: weighted partial-sum; thread owns (ci, 16 pos) ----
    {
        const int ci = tid >> 1, pbase = (tid & 1) * 16;
        float o[16];
        #pragma unroll
        for (int i = 0; i < 16; ++i) o[i] = 0.f;
        for (int s = 0; s < SEG; ++s) {
            const f16* pb = pacc + ((size_t)(bidx*SEG + s) * CI + ci) * NN + n0 + pbase;
            f16x8 v0 = *reinterpret_cast<const f16x8*>(pb);
            f16x8 v1 = *reinterpret_cast<const f16x8*>(pb + 8);
            #pragma unroll
            for (int i = 0; i < 8; ++i) {
                o[i]     = fmaf(wl_lds[s][pbase + i],     (float)v0[i], o[i]);
                o[8 + i] = fmaf(wl_lds[s][pbase + 8 + i], (float)v1[i], o[8 + i]);
            }
        }
        #pragma unroll
        for (int i = 0; i < 16; ++i)
            yls[(pbase + i)*136 + ci] = (f16)o[i];
    }
    __syncthreads();

    // ---- phase 2: GEMM 32 pos x 128 k x 256 ci ----
    const int wid = tid >> 6, lane = tid & 63;
    const int l15 = lane & 15, lg = lane >> 4;

    f32x4 acc[2][4];
    #pragma unroll
    for (int pt = 0; pt < 2; ++pt)
        #pragma unroll
        for (int t = 0; t < 4; ++t) acc[pt][t] = (f32x4){0.f,0.f,0.f,0.f};

    const f16* wb = WoT + (size_t)(wid*64 + l15)*CI + lg*8;
    #pragma unroll
    for (int kk = 0; kk < 4; ++kk) {
        f16x8 a0 = *reinterpret_cast<const f16x8*>(&yls[l15*136 + kk*32 + lg*8]);
        f16x8 a1 = *reinterpret_cast<const f16x8*>(&yls[(16 + l15)*136 + kk*32 + lg*8]);
        #pragma unroll
        for (int t = 0; t < 4; ++t) {
            f16x8 bfr = *reinterpret_cast<const f16x8*>(wb + (size_t)t*16*CI + kk*32);
            acc[0][t] = __builtin_amdgcn_mfma_f32_16x16x32_f16(a0, bfr, acc[0][t], 0, 0, 0);
            acc[1][t] = __builtin_amdgcn_mfma_f32_16x16x32_f16(a1, bfr, acc[1][t], 0, 0, 0);
        }
    }

    #pragma unroll
    for (int t = 0; t < 4; ++t) {
        const int ci = wid*64 + t*16 + l15;
        const float sc = bnsc[ci], sh = bnsh[ci];
        #pragma unroll
        for (int pt = 0; pt < 2; ++pt)
            #pragma unroll
            for (int r = 0; r < 4; ++r) {
                const size_t idx = (size_t)(p0 + pt*16 + lg*4 + r)*CC + ci;
                out[idx] = x[idx] + fmaf(sc, acc[pt][t][r], sh);
            }
    }
}

extern "C" void kernel_launch(void* const* d_in, const int* in_sizes, int n_in,
                              void* d_out, int out_size, void* d_ws, size_t ws_size,
                              hipStream_t stream)
{
    const float* x     = (const float*)d_in[0];
    const float* Wg    = (const float*)d_in[1];
    const float* bg    = (const float*)d_in[2];
    const float* Wt    = (const float*)d_in[3];
    const float* bt    = (const float*)d_in[4];
    const float* Wp    = (const float*)d_in[5];
    const float* bp    = (const float*)d_in[6];
    const float* Wo    = (const float*)d_in[7];
    const float* bo    = (const float*)d_in[8];
    const float* gamma = (const float*)d_in[9];
    const float* beta  = (const float*)d_in[10];
    const float* mmean = (const float*)d_in[11];
    const float* mvar  = (const float*)d_in[12];
    float* out = (float*)d_out;

    const size_t PB = (size_t)BB * NN * CI;                 // 1,605,632
    f16*   th   = (f16*)d_ws;                               // 3.2 MB
    f16*   ph   = th + PB;                                  // 3.2 MB
    f16*   gT   = ph + PB;                                  // 3.2 MB (tiled layout)
    f16*   pacc = gT + PB;                                  // BB*SEG*NN*CI f16 = 22.5 MB
    float* pml  = (float*)(pacc + (size_t)BB * SEG * NN * CI);  // 0.7 MB
    f16*   WallT= (f16*)(pml + (size_t)BB * SEG * NN * 2);  // 197 KB
    f16*   WoT  = WallT + 384*256;                          // 66 KB
    float* ball = (float*)(WoT + 256*CI);                   // 1.5 KB
    float* bnsc = ball + 384;
    float* bnsh = bnsc + 256;

    prep_kernel<<<516, 256, 0, stream>>>(Wg, Wt, Wp, Wo, bg, bt, bp, bo,
                                         gamma, beta, mmean, mvar,
                                         WallT, WoT, ball, bnsc, bnsh);
    proj_gemm<<<BB * NN / 32, 256, 0, stream>>>(x, WallT, ball, th, ph, gT);
    attn_kernel<<<dim3(NN / 128, SEG, BB), 256, 0, stream>>>(th, ph, gT, pacc, pml);
    out_gemm<<<BB * NN / 32, 256, 0, stream>>>(x, pacc, pml, WoT, bnsc, bnsh, out);
}